// Round 2
// baseline (3186.206 us; speedup 1.0000x reference)
//
#include <hip/hip_runtime.h>
#include <math.h>

#define CC    192
#define TT    8
#define HH    56
#define WWD   56
#define PP    3136      // H*W
#define NTOK  100352    // 32*56*56
#define NSEQ  12544     // 4*56*56

__device__ __forceinline__ float gelu_f(float v) {
  return 0.5f * v * (1.0f + erff(v * 0.70710678f));
}

// ---------------- weight transpose: out[(i*K+k)*192+o] = in[(o*192+i)*K+k] ----------------
__global__ __launch_bounds__(256) void k_tw(const float* __restrict__ in,
                                            float* __restrict__ out, int K) {
  int idx = blockIdx.x * 256 + threadIdx.x;
  int total = CC * CC * K;
  if (idx >= total) return;
  int o = idx % CC;
  int rest = idx / CC;          // i*K + k
  int k = rest % K;
  int i = rest / K;
  out[idx] = in[(o * CC + i) * K + k];
}

// ---------------- fused input projection GEMM: [x] @ [Wf | Wft], scatter outputs ----------------
__global__ __launch_bounds__(256) void k_in(const float* __restrict__ x,
    const float* __restrict__ Wf, const float* __restrict__ bf,
    const float* __restrict__ Wft, const float* __restrict__ bft,
    float* __restrict__ QS, float* __restrict__ CS, float* __restrict__ GS,
    float* __restrict__ CT, float* __restrict__ GT)
{
  __shared__ __align__(16) float As[32][68];
  __shared__ __align__(16) float Bs[32][68];
  const int tid = threadIdx.x;
  const int tx = tid & 15, ty = tid >> 4;
  const int row0 = blockIdx.y * 64;
  const int col0 = blockIdx.x * 64;
  float acc[4][4] = {};
  for (int kb = 0; kb < 192; kb += 32) {
    {
      int m = tid >> 3;
      int kk = (tid & 7) << 2;
      #pragma unroll
      for (int it = 0; it < 2; ++it) {
        int mm = m + it * 32;
        float4 v = *reinterpret_cast<const float4*>(x + (size_t)(row0 + mm) * CC + kb + kk);
        As[kk + 0][mm] = v.x; As[kk + 1][mm] = v.y;
        As[kk + 2][mm] = v.z; As[kk + 3][mm] = v.w;
      }
      int krb = tid >> 4;
      int nj = (tid & 15) << 2;
      #pragma unroll
      for (int it = 0; it < 2; ++it) {
        int kr = krb + it * 16;
        int c = kb + kr;
        #pragma unroll
        for (int u = 0; u < 4; ++u) {
          int j = col0 + nj + u;
          float wv = 0.0f;
          if (j < 387) wv = Wf[c * 387 + j];
          else if (j < 582) wv = Wft[c * 195 + (j - 387)];
          Bs[kr][nj + u] = wv;
        }
      }
    }
    __syncthreads();
    #pragma unroll
    for (int kk = 0; kk < 32; ++kk) {
      float4 a = *reinterpret_cast<const float4*>(&As[kk][ty << 2]);
      float4 b = *reinterpret_cast<const float4*>(&Bs[kk][tx << 2]);
      float av[4] = {a.x, a.y, a.z, a.w};
      float bv[4] = {b.x, b.y, b.z, b.w};
      #pragma unroll
      for (int i = 0; i < 4; ++i) {
        #pragma unroll
        for (int j = 0; j < 4; ++j)
          acc[i][j] = fmaf(av[i], bv[j], acc[i][j]);
      }
    }
    __syncthreads();
  }
  #pragma unroll
  for (int i = 0; i < 4; ++i) {
    int tk = row0 + (ty << 2) + i;
    int bb = tk / PP;
    int hw = tk - bb * PP;
    size_t ctbase = ((size_t)((bb >> 3) * PP + hw) * 8 + (size_t)(bb & 7));
    #pragma unroll
    for (int j2 = 0; j2 < 4; ++j2) {
      int j = col0 + (tx << 2) + j2;
      if (j >= 582) continue;
      float bias = (j < 387) ? bf[j] : bft[j - 387];
      float val = acc[i][j2] + bias;
      if (j < 192)      QS[(size_t)tk * CC + j] = val;
      else if (j < 384) CS[(size_t)tk * CC + (j - 192)] = val;
      else if (j < 387) GS[(size_t)tk * 3 + (j - 384)] = val;
      else {
        int jj = j - 387;
        if (jj < 192) CT[ctbase * CC + jj] = val;
        else          GT[ctbase * 3 + (jj - 192)] = val;
      }
    }
  }
}

// ---------------- temporal pipeline: conv3 -> gelu -> conv5 -> gelu -> gated sum -> Wht GEMM ----------------
// 4 sequences (n) per block, 256 threads: o_id = tid&31 (6 rows each), cg = tid>>5,
// n_id = cg>>1, th = (cg&1)*4 (4 of the 8 timesteps).
// MT is written in SPATIAL token order (into d_out) so the final GEMM is row-local.
__global__ __launch_bounds__(256) void k_t(const float* __restrict__ CT,
    const float* __restrict__ GT, const float* __restrict__ TW0T,
    const float* __restrict__ TW1T, const float* __restrict__ WHTT,
    const float* __restrict__ bht, float* __restrict__ MT)
{
  __shared__ __align__(16) float bufA[4 * 8 * 192];   // ctx, later ctx_all  (24 KB)
  __shared__ __align__(16) float bufB[4 * 8 * 192];   // c1                  (24 KB)
  __shared__ __align__(16) float wbuf[4 * 5 * 192];   // weight chunk        (15 KB)
  __shared__ float gbuf[96];
  const int tid = threadIdx.x;
  const int n0 = blockIdx.x * 4;
  const int o_id = tid & 31;
  const int cg = tid >> 5;
  const int n_id = cg >> 1;
  const int th = (cg & 1) << 2;
  const int nbase = n_id * 8;

  {
    const float4* src = reinterpret_cast<const float4*>(CT + (size_t)n0 * 1536);
    float4* dst = reinterpret_cast<float4*>(bufA);
    for (int i = tid; i < 1536; i += 256) dst[i] = src[i];
    if (tid < 96) gbuf[tid] = GT[(size_t)n0 * 24 + tid];
  }

  // ---- conv K=3 (pad 1) ----
  float acc[6][4] = {};
  for (int ib = 0; ib < 192; ib += 6) {
    __syncthreads();
    {
      const float4* src = reinterpret_cast<const float4*>(TW0T + ib * 576);
      float4* dst = reinterpret_cast<float4*>(wbuf);
      for (int i = tid; i < 864; i += 256) dst[i] = src[i];   // 6*3*192/4
    }
    __syncthreads();
    #pragma unroll
    for (int ii = 0; ii < 6; ++ii) {
      float b8[8];
      #pragma unroll
      for (int t = 0; t < 8; ++t) b8[t] = bufA[(nbase + t) * 192 + ib + ii];
      #pragma unroll
      for (int k = 0; k < 3; ++k) {
        float a[6];
        #pragma unroll
        for (int r = 0; r < 6; ++r) a[r] = wbuf[(ii * 3 + k) * 192 + o_id + 32 * r];
        #pragma unroll
        for (int tl = 0; tl < 4; ++tl) {
          int ts = th + tl + k - 1;
          if (ts >= 0 && ts < 8) {
            #pragma unroll
            for (int r = 0; r < 6; ++r) acc[r][tl] = fmaf(a[r], b8[ts], acc[r][tl]);
          }
        }
      }
    }
  }
  __syncthreads();
  // c1 -> bufB ; ctx_all g0 term -> bufA
  #pragma unroll
  for (int r = 0; r < 6; ++r) {
    int o = o_id + 32 * r;
    #pragma unroll
    for (int tl = 0; tl < 4; ++tl) {
      int t = th + tl;
      float c1 = gelu_f(acc[r][tl]);
      bufB[(nbase + t) * 192 + o] = c1;
      bufA[(nbase + t) * 192 + o] = c1 * gbuf[(nbase + t) * 3 + 0];
    }
  }

  // ---- conv K=5 (pad 2) ----
  float acc2[6][4] = {};
  for (int ib = 0; ib < 192; ib += 4) {
    __syncthreads();
    {
      const float4* src = reinterpret_cast<const float4*>(TW1T + ib * 960);
      float4* dst = reinterpret_cast<float4*>(wbuf);
      for (int i = tid; i < 960; i += 256) dst[i] = src[i];   // 4*5*192/4
    }
    __syncthreads();
    #pragma unroll
    for (int ii = 0; ii < 4; ++ii) {
      float b8[8];
      #pragma unroll
      for (int t = 0; t < 8; ++t) b8[t] = bufB[(nbase + t) * 192 + ib + ii];
      #pragma unroll
      for (int k = 0; k < 5; ++k) {
        float a[6];
        #pragma unroll
        for (int r = 0; r < 6; ++r) a[r] = wbuf[(ii * 5 + k) * 192 + o_id + 32 * r];
        #pragma unroll
        for (int tl = 0; tl < 4; ++tl) {
          int ts = th + tl + k - 2;
          if (ts >= 0 && ts < 8) {
            #pragma unroll
            for (int r = 0; r < 6; ++r) acc2[r][tl] = fmaf(a[r], b8[ts], acc2[r][tl]);
          }
        }
      }
    }
  }
  // c2 contributions + temporal-mean term (partner half via shfl_xor 32)
  #pragma unroll
  for (int r = 0; r < 6; ++r) {
    int o = o_id + 32 * r;
    float c2v[4]; float s = 0.0f;
    #pragma unroll
    for (int tl = 0; tl < 4; ++tl) { c2v[tl] = gelu_f(acc2[r][tl]); s += c2v[tl]; }
    s += __shfl_xor(s, 32, 64);
    float gm = gelu_f(s * 0.125f);
    #pragma unroll
    for (int tl = 0; tl < 4; ++tl) {
      int t = th + tl;
      bufA[(nbase + t) * 192 + o] += c2v[tl] * gbuf[(nbase + t) * 3 + 1]
                                   + gm * gbuf[(nbase + t) * 3 + 2];
    }
  }

  // ---- mod_t = Wht @ ctx_all + bht ----
  float acc3[6][4] = {};
  for (int ib = 0; ib < 192; ib += 16) {
    __syncthreads();
    {
      const float4* src = reinterpret_cast<const float4*>(WHTT + ib * 192);
      float4* dst = reinterpret_cast<float4*>(wbuf);
      for (int i = tid; i < 768; i += 256) dst[i] = src[i];   // 16*192/4
    }
    __syncthreads();
    #pragma unroll
    for (int ii = 0; ii < 16; ++ii) {
      float b4[4];
      #pragma unroll
      for (int tl = 0; tl < 4; ++tl) b4[tl] = bufA[(nbase + th + tl) * 192 + ib + ii];
      float a[6];
      #pragma unroll
      for (int r = 0; r < 6; ++r) a[r] = wbuf[ii * 192 + o_id + 32 * r];
      #pragma unroll
      for (int r = 0; r < 6; ++r) {
        #pragma unroll
        for (int tl = 0; tl < 4; ++tl)
          acc3[r][tl] = fmaf(a[r], b4[tl], acc3[r][tl]);
      }
    }
  }
  // write in SPATIAL order: tk = (bgroup*8 + t)*PP + hw
  const int n = n0 + n_id;
  const int bgroup = n / PP;
  const int hw = n - bgroup * PP;
  #pragma unroll
  for (int r = 0; r < 6; ++r) {
    int o = o_id + 32 * r;
    float bo = bht[o];
    #pragma unroll
    for (int tl = 0; tl < 4; ++tl) {
      int t = th + tl;
      size_t tk = (size_t)(bgroup * 8 + t) * PP + hw;
      MT[tk * CC + o] = acc3[r][tl] + bo;
    }
  }
}

// ---------------- depthwise 3x3 + gelu (channel-last, float4 over c) ----------------
__global__ __launch_bounds__(256) void k_dw3(const float* __restrict__ IN,
    const float* __restrict__ fw, float* __restrict__ OUT)
{
  int idx = blockIdx.x * 256 + threadIdx.x;
  int tk = idx / 48;
  int cq = idx - tk * 48;
  if (tk >= NTOK) return;
  int c0 = cq << 2;
  int bb = tk / PP;
  int hw = tk - bb * PP;
  int h = hw / WWD;
  int w = hw - h * WWD;
  float wreg[9][4];
  #pragma unroll
  for (int kk = 0; kk < 9; ++kk) {
    #pragma unroll
    for (int u = 0; u < 4; ++u) wreg[kk][u] = fw[(c0 + u) * 9 + kk];
  }
  float a0 = 0.f, a1 = 0.f, a2 = 0.f, a3 = 0.f;
  const size_t rowbase = (size_t)bb * PP;
  #pragma unroll
  for (int kh = 0; kh < 3; ++kh) {
    int hh = h + kh - 1;
    if (hh < 0 || hh >= HH) continue;
    #pragma unroll
    for (int kw = 0; kw < 3; ++kw) {
      int wp = w + kw - 1;
      if (wp < 0 || wp >= WWD) continue;
      float4 v = *reinterpret_cast<const float4*>(IN + (rowbase + hh * WWD + wp) * CC + c0);
      int kk = kh * 3 + kw;
      a0 = fmaf(v.x, wreg[kk][0], a0);
      a1 = fmaf(v.y, wreg[kk][1], a1);
      a2 = fmaf(v.z, wreg[kk][2], a2);
      a3 = fmaf(v.w, wreg[kk][3], a3);
    }
  }
  float4 o;
  o.x = gelu_f(a0); o.y = gelu_f(a1); o.z = gelu_f(a2); o.w = gelu_f(a3);
  *reinterpret_cast<float4*>(OUT + (size_t)tk * CC + c0) = o;
}

// ---------------- depthwise 5x5 + gelu ----------------
__global__ __launch_bounds__(256) void k_dw5(const float* __restrict__ IN,
    const float* __restrict__ fw, float* __restrict__ OUT)
{
  int idx = blockIdx.x * 256 + threadIdx.x;
  int tk = idx / 48;
  int cq = idx - tk * 48;
  if (tk >= NTOK) return;
  int c0 = cq << 2;
  int bb = tk / PP;
  int hw = tk - bb * PP;
  int h = hw / WWD;
  int w = hw - h * WWD;
  float a0 = 0.f, a1 = 0.f, a2 = 0.f, a3 = 0.f;
  const size_t rowbase = (size_t)bb * PP;
  #pragma unroll
  for (int kh = 0; kh < 5; ++kh) {
    int hh = h + kh - 2;
    if (hh < 0 || hh >= HH) continue;
    #pragma unroll
    for (int kw = 0; kw < 5; ++kw) {
      int wp = w + kw - 2;
      if (wp < 0 || wp >= WWD) continue;
      float4 v = *reinterpret_cast<const float4*>(IN + (rowbase + hh * WWD + wp) * CC + c0);
      int kk = kh * 5 + kw;
      a0 = fmaf(v.x, fw[(c0 + 0) * 25 + kk], a0);
      a1 = fmaf(v.y, fw[(c0 + 1) * 25 + kk], a1);
      a2 = fmaf(v.z, fw[(c0 + 2) * 25 + kk], a2);
      a3 = fmaf(v.w, fw[(c0 + 3) * 25 + kk], a3);
    }
  }
  float4 o;
  o.x = gelu_f(a0); o.y = gelu_f(a1); o.z = gelu_f(a2); o.w = gelu_f(a3);
  *reinterpret_cast<float4*>(OUT + (size_t)tk * CC + c0) = o;
}

// ---------------- spatial global mean (two-pass, deterministic) ----------------
__global__ __launch_bounds__(192) void k_mean(const float* __restrict__ C2S,
                                              float* __restrict__ GMpart)
{
  int bb = blockIdx.x / 49;
  int chunk = blockIdx.x - bb * 49;
  int c = threadIdx.x;
  float s = 0.f;
  int hw0 = chunk * 64;
  const float* p = C2S + ((size_t)bb * PP + hw0) * CC + c;
  for (int i = 0; i < 64; ++i) s += p[(size_t)i * CC];
  GMpart[(size_t)chunk * 6144 + bb * CC + c] = s;
}

__global__ __launch_bounds__(256) void k_gmg(const float* __restrict__ GMpart,
                                             float* __restrict__ GMg)
{
  int i = blockIdx.x * 256 + threadIdx.x;
  if (i >= 6144) return;
  float s = 0.f;
  for (int p = 0; p < 49; ++p) s += GMpart[(size_t)p * 6144 + i];
  GMg[i] = gelu_f(s * (1.0f / 3136.0f));
}

// ---------------- mod GEMM: MOD = (c1*g0 + c2*g1 + gmean*g2) @ Wh^T + bh ----------------
// Writes MOD IN-PLACE over C1 (block owns full 64x192 rows; all C1 reads precede writes).
__global__ __launch_bounds__(256) void k_mod(float* __restrict__ C1MOD,
    const float* __restrict__ C2S, const float* __restrict__ GS,
    const float* __restrict__ GMg, const float* __restrict__ WhT,
    const float* __restrict__ bh)
{
  __shared__ __align__(16) float As[32][68];
  __shared__ __align__(16) float Bs[32][200];
  const int tid = threadIdx.x;
  const int tx = tid & 15, ty = tid >> 4;
  const int row0 = blockIdx.x * 64;
  float acc[4][12] = {};
  for (int kb = 0; kb < 192; kb += 32) {
    {
      int m = tid >> 3;
      int kk = (tid & 7) << 2;
      #pragma unroll
      for (int it = 0; it < 2; ++it) {
        int mm = m + it * 32;
        int tk = row0 + mm;
        int bb = tk / PP;
        size_t base = (size_t)tk * CC + kb + kk;
        float4 v1 = *reinterpret_cast<const float4*>(C1MOD + base);
        float4 v2 = *reinterpret_cast<const float4*>(C2S + base);
        float4 vg = *reinterpret_cast<const float4*>(GMg + bb * CC + kb + kk);
        float g0 = GS[(size_t)tk * 3 + 0];
        float g1 = GS[(size_t)tk * 3 + 1];
        float g2 = GS[(size_t)tk * 3 + 2];
        As[kk + 0][mm] = v1.x * g0 + v2.x * g1 + vg.x * g2;
        As[kk + 1][mm] = v1.y * g0 + v2.y * g1 + vg.y * g2;
        As[kk + 2][mm] = v1.z * g0 + v2.z * g1 + vg.z * g2;
        As[kk + 3][mm] = v1.w * g0 + v2.w * g1 + vg.w * g2;
      }
      #pragma unroll
      for (int it = 0; it < 6; ++it) {
        int li = tid + it * 256;
        int kr = li / 48;
        int cq = (li - kr * 48) << 2;
        float4 wv = *reinterpret_cast<const float4*>(WhT + (size_t)(kb + kr) * CC + cq);
        Bs[kr][cq + 0] = wv.x; Bs[kr][cq + 1] = wv.y;
        Bs[kr][cq + 2] = wv.z; Bs[kr][cq + 3] = wv.w;
      }
    }
    __syncthreads();
    #pragma unroll
    for (int kk2 = 0; kk2 < 32; ++kk2) {
      float4 a = *reinterpret_cast<const float4*>(&As[kk2][ty << 2]);
      float av[4] = {a.x, a.y, a.z, a.w};
      #pragma unroll
      for (int s = 0; s < 3; ++s) {
        float4 b = *reinterpret_cast<const float4*>(&Bs[kk2][(tx << 2) + (s << 6)]);
        float bv[4] = {b.x, b.y, b.z, b.w};
        #pragma unroll
        for (int i = 0; i < 4; ++i) {
          #pragma unroll
          for (int j = 0; j < 4; ++j)
            acc[i][s * 4 + j] = fmaf(av[i], bv[j], acc[i][s * 4 + j]);
        }
      }
    }
    __syncthreads();
  }
  #pragma unroll
  for (int i = 0; i < 4; ++i) {
    int tk = row0 + (ty << 2) + i;
    #pragma unroll
    for (int s = 0; s < 3; ++s) {
      #pragma unroll
      for (int j = 0; j < 4; ++j) {
        int o = (tx << 2) + (s << 6) + j;
        C1MOD[(size_t)tk * CC + o] = acc[i][s * 4 + j] + bh[o];
      }
    }
  }
}

// ---------------- output GEMM: out = (q * mod * mod_t) @ Wp + bp ----------------
// MT lives in d_out (spatial order) and is overwritten IN-PLACE (row-local blocks).
__global__ __launch_bounds__(256) void k_out(const float* __restrict__ QS,
    const float* __restrict__ MOD, float* MTout,
    const float* __restrict__ Wp, const float* __restrict__ bp)
{
  __shared__ __align__(16) float As[32][68];
  __shared__ __align__(16) float Bs[32][200];
  const int tid = threadIdx.x;
  const int tx = tid & 15, ty = tid >> 4;
  const int row0 = blockIdx.x * 64;
  float acc[4][12] = {};
  for (int kb = 0; kb < 192; kb += 32) {
    {
      int m = tid >> 3;
      int kk = (tid & 7) << 2;
      #pragma unroll
      for (int it = 0; it < 2; ++it) {
        int mm = m + it * 32;
        int tk = row0 + mm;
        size_t base = (size_t)tk * CC + kb + kk;
        float4 q  = *reinterpret_cast<const float4*>(QS + base);
        float4 md = *reinterpret_cast<const float4*>(MOD + base);
        float4 mt = *reinterpret_cast<const float4*>(MTout + base);
        As[kk + 0][mm] = q.x * md.x * mt.x;
        As[kk + 1][mm] = q.y * md.y * mt.y;
        As[kk + 2][mm] = q.z * md.z * mt.z;
        As[kk + 3][mm] = q.w * md.w * mt.w;
      }
      #pragma unroll
      for (int it = 0; it < 6; ++it) {
        int li = tid + it * 256;
        int kr = li / 48;
        int cq = (li - kr * 48) << 2;
        float4 wv = *reinterpret_cast<const float4*>(Wp + (size_t)(kb + kr) * CC + cq);
        Bs[kr][cq + 0] = wv.x; Bs[kr][cq + 1] = wv.y;
        Bs[kr][cq + 2] = wv.z; Bs[kr][cq + 3] = wv.w;
      }
    }
    __syncthreads();
    #pragma unroll
    for (int kk2 = 0; kk2 < 32; ++kk2) {
      float4 a = *reinterpret_cast<const float4*>(&As[kk2][ty << 2]);
      float av[4] = {a.x, a.y, a.z, a.w};
      #pragma unroll
      for (int s = 0; s < 3; ++s) {
        float4 b = *reinterpret_cast<const float4*>(&Bs[kk2][(tx << 2) + (s << 6)]);
        float bv[4] = {b.x, b.y, b.z, b.w};
        #pragma unroll
        for (int i = 0; i < 4; ++i) {
          #pragma unroll
          for (int j = 0; j < 4; ++j)
            acc[i][s * 4 + j] = fmaf(av[i], bv[j], acc[i][s * 4 + j]);
        }
      }
    }
    __syncthreads();
  }
  #pragma unroll
  for (int i = 0; i < 4; ++i) {
    int tk = row0 + (ty << 2) + i;
    #pragma unroll
    for (int s = 0; s < 3; ++s) {
      #pragma unroll
      for (int j = 0; j < 4; ++j) {
        int o = (tx << 2) + (s << 6) + j;
        MTout[(size_t)tk * CC + o] = acc[i][s * 4 + j] + bp[o];
      }
    }
  }
}

extern "C" void kernel_launch(void* const* d_in, const int* in_sizes, int n_in,
                              void* d_out, int out_size, void* d_ws, size_t ws_size,
                              hipStream_t stream)
{
  (void)in_sizes; (void)n_in; (void)out_size; (void)ws_size;
  const float* x   = (const float*)d_in[0];
  const float* Wf  = (const float*)d_in[1];
  const float* bf  = (const float*)d_in[2];
  const float* Wft = (const float*)d_in[3];
  const float* bft = (const float*)d_in[4];
  const float* fw0 = (const float*)d_in[5];
  const float* fw1 = (const float*)d_in[6];
  const float* tw0 = (const float*)d_in[7];
  const float* tw1 = (const float*)d_in[8];
  const float* Wh  = (const float*)d_in[9];
  const float* bh  = (const float*)d_in[10];
  const float* Wht = (const float*)d_in[11];
  const float* bht = (const float*)d_in[12];
  const float* Wp  = (const float*)d_in[13];
  const float* bp  = (const float*)d_in[14];

  float* ws = (float*)d_ws;
  const size_t SZ = (size_t)NTOK * CC;          // 19,267,584 floats (77 MB)
  // 3 large slots + d_out reuse; total ws ~236 MB
  float* QS     = ws + 0 * SZ;                  // q (spatial)              [phase1..8]
  float* WS1    = ws + 1 * SZ;                  // ctx_s -> c2_s
  float* WS2    = ws + 2 * SZ;                  // ctx_t -> c1_s -> MOD
  float* MT     = (float*)d_out;                // mod_t (SPATIAL order) -> out, in-place
  float* GS     = ws + 3 * SZ;                  // gates_s [tok][3]
  float* GT     = GS + (size_t)NTOK * 3;        // gates_t [n*8+t][3]
  float* GMpart = GT + (size_t)NTOK * 3;        // 49 x 6144 partial sums
  float* GMg    = GMpart + 49 * 6144;           // gelu(mean) [32][192]
  float* TW0T   = GMg + 6144;                   // tw0 transposed (576 x 192)
  float* TW1T   = TW0T + 576 * 192;             // tw1 transposed (960 x 192)
  float* WHTT   = TW1T + 960 * 192;             // Wht^T (192 x 192)
  float* WhT    = WHTT + 192 * 192;             // Wh^T  (192 x 192)

  k_tw<<<432, 256, 0, stream>>>(tw0, TW0T, 3);
  k_tw<<<720, 256, 0, stream>>>(tw1, TW1T, 5);
  k_tw<<<144, 256, 0, stream>>>(Wht, WHTT, 1);
  k_tw<<<144, 256, 0, stream>>>(Wh,  WhT,  1);

  k_in<<<dim3(10, 1568), 256, 0, stream>>>(x, Wf, bf, Wft, bft, QS, WS1, GS, WS2, GT);
  k_t<<<3136, 256, 0, stream>>>(WS2, GT, TW0T, TW1T, WHTT, bht, MT);

  k_dw3<<<18816, 256, 0, stream>>>(WS1, fw0, WS2);      // ctx -> c1 (over ctx_t)
  k_dw5<<<18816, 256, 0, stream>>>(WS2, fw1, WS1);      // c1  -> c2 (over ctx)
  k_mean<<<32 * 49, 192, 0, stream>>>(WS1, GMpart);
  k_gmg<<<24, 256, 0, stream>>>(GMpart, GMg);

  k_mod<<<1568, 256, 0, stream>>>(WS2, WS1, GS, GMg, WhT, bh);        // MOD over C1
  k_out<<<1568, 256, 0, stream>>>(QS, WS2, MT, Wp, bp);               // out over MT
}

// Round 3
// 1710.034 us; speedup vs baseline: 1.8632x; 1.8632x over previous
//
#include <hip/hip_runtime.h>
#include <math.h>

#define CC    192
#define TT    8
#define HH    56
#define WWD   56
#define PP    3136      // H*W
#define NTOK  100352    // 32*56*56
#define NSEQ  12544     // 4*56*56

typedef __attribute__((ext_vector_type(8))) short short8v;  // 8 bf16 (4 VGPR)
typedef __attribute__((ext_vector_type(4))) float f32x4;
using u16 = unsigned short;

__device__ __forceinline__ float gelu_f(float v) {
  return 0.5f * v * (1.0f + erff(v * 0.70710678f));
}

__device__ __forceinline__ u16 bf16hi(float f) {
  unsigned u = __builtin_bit_cast(unsigned, f);
  u += 0x7fffu + ((u >> 16) & 1u);
  return (u16)(u >> 16);
}
__device__ __forceinline__ float bf2f(u16 h) {
  unsigned u = ((unsigned)h) << 16;
  return __builtin_bit_cast(float, u);
}

// ---------------- weight transpose (fp32, for k_mod): out[i*192+o] = in[o*192+i] ----------------
__global__ __launch_bounds__(256) void k_tw(const float* __restrict__ in,
                                            float* __restrict__ out, int K) {
  int idx = blockIdx.x * 256 + threadIdx.x;
  int total = CC * CC * K;
  if (idx >= total) return;
  int o = idx % CC;
  int rest = idx / CC;          // i*K + k
  int k = rest % K;
  int i = rest / K;
  out[idx] = in[(o * CC + i) * K + k];
}

// ---------------- weight split to bf16 hi/lo, layout [k][o][i] ----------------
__global__ __launch_bounds__(256) void k_wsplit(const float* __restrict__ in,
    u16* __restrict__ hi, u16* __restrict__ lo, int K) {
  int idx = blockIdx.x * 256 + threadIdx.x;
  int total = CC * CC * K;
  if (idx >= total) return;
  int i = idx % CC;
  int rest = idx / CC;
  int o = rest % CC;
  int k = rest / CC;
  float f = in[(o * CC + i) * K + k];
  u16 h = bf16hi(f);
  hi[idx] = h;
  lo[idx] = bf16hi(f - bf2f(h));
}

// ---------------- fused input projection GEMM: [x] @ [Wf | Wft], scatter outputs ----------------
__global__ __launch_bounds__(256) void k_in(const float* __restrict__ x,
    const float* __restrict__ Wf, const float* __restrict__ bf,
    const float* __restrict__ Wft, const float* __restrict__ bft,
    float* __restrict__ QS, float* __restrict__ CS, float* __restrict__ GS,
    float* __restrict__ CT, float* __restrict__ GT)
{
  __shared__ __align__(16) float As[32][68];
  __shared__ __align__(16) float Bs[32][68];
  const int tid = threadIdx.x;
  const int tx = tid & 15, ty = tid >> 4;
  const int row0 = blockIdx.y * 64;
  const int col0 = blockIdx.x * 64;
  float acc[4][4] = {};
  for (int kb = 0; kb < 192; kb += 32) {
    {
      int m = tid >> 3;
      int kk = (tid & 7) << 2;
      #pragma unroll
      for (int it = 0; it < 2; ++it) {
        int mm = m + it * 32;
        float4 v = *reinterpret_cast<const float4*>(x + (size_t)(row0 + mm) * CC + kb + kk);
        As[kk + 0][mm] = v.x; As[kk + 1][mm] = v.y;
        As[kk + 2][mm] = v.z; As[kk + 3][mm] = v.w;
      }
      int krb = tid >> 4;
      int nj = (tid & 15) << 2;
      #pragma unroll
      for (int it = 0; it < 2; ++it) {
        int kr = krb + it * 16;
        int c = kb + kr;
        #pragma unroll
        for (int u = 0; u < 4; ++u) {
          int j = col0 + nj + u;
          float wv = 0.0f;
          if (j < 387) wv = Wf[c * 387 + j];
          else if (j < 582) wv = Wft[c * 195 + (j - 387)];
          Bs[kr][nj + u] = wv;
        }
      }
    }
    __syncthreads();
    #pragma unroll
    for (int kk = 0; kk < 32; ++kk) {
      float4 a = *reinterpret_cast<const float4*>(&As[kk][ty << 2]);
      float4 b = *reinterpret_cast<const float4*>(&Bs[kk][tx << 2]);
      float av[4] = {a.x, a.y, a.z, a.w};
      float bv[4] = {b.x, b.y, b.z, b.w};
      #pragma unroll
      for (int i = 0; i < 4; ++i) {
        #pragma unroll
        for (int j = 0; j < 4; ++j)
          acc[i][j] = fmaf(av[i], bv[j], acc[i][j]);
      }
    }
    __syncthreads();
  }
  #pragma unroll
  for (int i = 0; i < 4; ++i) {
    int tk = row0 + (ty << 2) + i;
    int bb = tk / PP;
    int hw = tk - bb * PP;
    size_t ctbase = ((size_t)((bb >> 3) * PP + hw) * 8 + (size_t)(bb & 7));
    #pragma unroll
    for (int j2 = 0; j2 < 4; ++j2) {
      int j = col0 + (tx << 2) + j2;
      if (j >= 582) continue;
      float bias = (j < 387) ? bf[j] : bft[j - 387];
      float val = acc[i][j2] + bias;
      if (j < 192)      QS[(size_t)tk * CC + j] = val;
      else if (j < 384) CS[(size_t)tk * CC + (j - 192)] = val;
      else if (j < 387) GS[(size_t)tk * 3 + (j - 384)] = val;
      else {
        int jj = j - 387;
        if (jj < 192) CT[ctbase * CC + jj] = val;
        else          GT[ctbase * 3 + (jj - 192)] = val;
      }
    }
  }
}

// ---------------- temporal pipeline, split-bf16 MFMA version ----------------
// 4 sequences/block, 4 waves; wave w owns out-channels [w*48, w*48+48).
// Fragments: A = weights [o][i] rows (global, bf16 hi/lo), B = activations (LDS, hi/lo).
// acc tiles: 3 rowtiles x 2 coltiles of 16x16; 3 MFMAs per (r,c,Kstep) for hi/lo split.
#define PADB 200
#define PADF 196
__global__ __launch_bounds__(256, 2) void k_t_mfma(
    const float* __restrict__ CT, const float* __restrict__ GT,
    const u16* __restrict__ W3h, const u16* __restrict__ W3l,
    const u16* __restrict__ W5h, const u16* __restrict__ W5l,
    const u16* __restrict__ WHh, const u16* __restrict__ WHl,
    const float* __restrict__ bht, float* __restrict__ MT)
{
  __shared__ __align__(16) u16 uA[2 * 48 * PADB];   // ctx hi|lo ; later sAll fp32 [32][PADF]
  __shared__ __align__(16) u16 uC[2 * 48 * PADB];   // c1 hi|lo
  __shared__ float gbuf[96];
  u16* ctxh = uA;
  u16* ctxl = uA + 48 * PADB;
  u16* c1h  = uC;
  u16* c1l  = uC + 48 * PADB;
  float* sAll = (float*)uA;                          // [32][PADF]

  const int tid  = threadIdx.x;
  const int lane = tid & 63;
  const int w    = tid >> 6;
  const int m0   = w * 48;
  const int lrow = lane & 15;
  const int lk   = (lane >> 4) * 8;   // K offset within 32-step
  const int orow = (lane >> 4) * 4;   // C/D row base within 16-tile
  const int n0   = blockIdx.x * 4;

  // ---- stage gates ----
  if (tid < 96) gbuf[tid] = GT[(size_t)n0 * 24 + tid];

  // ---- zero halo cols (p%12 in {0,1,10,11}) of ctx and c1, both hi/lo ----
  for (int i = tid; i < 16 * 96; i += 256) {
    int hc = i / 96, j = i - hc * 96;
    int s = hc >> 2, which = hc & 3;
    int pc = s * 12 + ((which < 2) ? which : (8 + which));   // 0,1,10,11
    ((unsigned*)&ctxh[pc * PADB])[j] = 0u;
    ((unsigned*)&ctxl[pc * PADB])[j] = 0u;
    ((unsigned*)&c1h [pc * PADB])[j] = 0u;
    ((unsigned*)&c1l [pc * PADB])[j] = 0u;
  }

  // ---- stage ctx: 4 seq * 8 t * 192 c fp32 -> bf16 hi/lo ----
  {
    const float4* src = (const float4*)(CT + (size_t)n0 * 1536);
    #pragma unroll
    for (int it = 0; it < 6; ++it) {
      int idx = tid + it * 256;           // 0..1535 float4
      int e = idx * 4;
      int s = e / 1536;
      int r2 = e - s * 1536;
      int t = r2 / 192;
      int c = r2 - t * 192;
      float4 v = src[idx];
      int pc = s * 12 + 2 + t;
      float vv[4] = {v.x, v.y, v.z, v.w};
      u16 hh[4], ll[4];
      #pragma unroll
      for (int u = 0; u < 4; ++u) {
        hh[u] = bf16hi(vv[u]);
        ll[u] = bf16hi(vv[u] - bf2f(hh[u]));
      }
      *(uint2*)&ctxh[pc * PADB + c] =
          make_uint2((unsigned)hh[0] | ((unsigned)hh[1] << 16),
                     (unsigned)hh[2] | ((unsigned)hh[3] << 16));
      *(uint2*)&ctxl[pc * PADB + c] =
          make_uint2((unsigned)ll[0] | ((unsigned)ll[1] << 16),
                     (unsigned)ll[2] | ((unsigned)ll[3] << 16));
    }
  }
  __syncthreads();

  // padded-col base per coltile for this lane
  int pcolBase[2];
  #pragma unroll
  for (int c = 0; c < 2; ++c) {
    int col = c * 16 + lrow;
    pcolBase[c] = (col >> 3) * 12 + 2 + (col & 7);
  }

  // ---- conv K=3 ----
  f32x4 acc[3][2] = {};
  for (int off = 0; off < 3; ++off) {
    int sh = off - 1;
    for (int kb = 0; kb < 6; ++kb) {
      int k0 = kb * 32;
      short8v ah[3], al[3], bh[2], bl[2];
      #pragma unroll
      for (int r = 0; r < 3; ++r) {
        size_t aoff = ((size_t)(off * 192 + m0 + r * 16 + lrow)) * 192 + k0 + lk;
        ah[r] = *(const short8v*)(W3h + aoff);
        al[r] = *(const short8v*)(W3l + aoff);
      }
      #pragma unroll
      for (int c = 0; c < 2; ++c) {
        int pc = pcolBase[c] + sh;
        bh[c] = *(const short8v*)&ctxh[pc * PADB + k0 + lk];
        bl[c] = *(const short8v*)&ctxl[pc * PADB + k0 + lk];
      }
      #pragma unroll
      for (int r = 0; r < 3; ++r)
        #pragma unroll
        for (int c = 0; c < 2; ++c) {
          acc[r][c] = __builtin_amdgcn_mfma_f32_16x16x32_bf16(ah[r], bh[c], acc[r][c], 0, 0, 0);
          acc[r][c] = __builtin_amdgcn_mfma_f32_16x16x32_bf16(ah[r], bl[c], acc[r][c], 0, 0, 0);
          acc[r][c] = __builtin_amdgcn_mfma_f32_16x16x32_bf16(al[r], bh[c], acc[r][c], 0, 0, 0);
        }
    }
  }
  __syncthreads();   // all ctx reads done before sAll overwrites uA

  // ---- conv3 epilogue: c1 = gelu(acc) -> uC ; sAll = c1*g0 ----
  #pragma unroll
  for (int r = 0; r < 3; ++r) {
    int o = m0 + r * 16 + orow;
    #pragma unroll
    for (int c = 0; c < 2; ++c) {
      int col = c * 16 + lrow;
      int pc = pcolBase[c];
      float g0 = gbuf[col * 3 + 0];
      f32x4 a = acc[r][c];
      u16 hh[4], ll[4];
      float cv[4];
      #pragma unroll
      for (int u = 0; u < 4; ++u) {
        float c1v = gelu_f(a[u]);
        hh[u] = bf16hi(c1v);
        ll[u] = bf16hi(c1v - bf2f(hh[u]));
        cv[u] = c1v * g0;
      }
      *(uint2*)&c1h[pc * PADB + o] =
          make_uint2((unsigned)hh[0] | ((unsigned)hh[1] << 16),
                     (unsigned)hh[2] | ((unsigned)hh[3] << 16));
      *(uint2*)&c1l[pc * PADB + o] =
          make_uint2((unsigned)ll[0] | ((unsigned)ll[1] << 16),
                     (unsigned)ll[2] | ((unsigned)ll[3] << 16));
      *(float4*)&sAll[col * PADF + o] = make_float4(cv[0], cv[1], cv[2], cv[3]);
    }
  }
  __syncthreads();

  // ---- conv K=5 ----
  f32x4 acc2[3][2] = {};
  for (int off = 0; off < 5; ++off) {
    int sh = off - 2;
    for (int kb = 0; kb < 6; ++kb) {
      int k0 = kb * 32;
      short8v ah[3], al[3], bh[2], bl[2];
      #pragma unroll
      for (int r = 0; r < 3; ++r) {
        size_t aoff = ((size_t)(off * 192 + m0 + r * 16 + lrow)) * 192 + k0 + lk;
        ah[r] = *(const short8v*)(W5h + aoff);
        al[r] = *(const short8v*)(W5l + aoff);
      }
      #pragma unroll
      for (int c = 0; c < 2; ++c) {
        int pc = pcolBase[c] + sh;
        bh[c] = *(const short8v*)&c1h[pc * PADB + k0 + lk];
        bl[c] = *(const short8v*)&c1l[pc * PADB + k0 + lk];
      }
      #pragma unroll
      for (int r = 0; r < 3; ++r)
        #pragma unroll
        for (int c = 0; c < 2; ++c) {
          acc2[r][c] = __builtin_amdgcn_mfma_f32_16x16x32_bf16(ah[r], bh[c], acc2[r][c], 0, 0, 0);
          acc2[r][c] = __builtin_amdgcn_mfma_f32_16x16x32_bf16(ah[r], bl[c], acc2[r][c], 0, 0, 0);
          acc2[r][c] = __builtin_amdgcn_mfma_f32_16x16x32_bf16(al[r], bh[c], acc2[r][c], 0, 0, 0);
        }
    }
  }

  // ---- conv5 epilogue: c2 = gelu(acc2); temporal mean; sAll += c2*g1 + gm*g2 ----
  #pragma unroll
  for (int r = 0; r < 3; ++r) {
    int o = m0 + r * 16 + orow;
    #pragma unroll
    for (int c = 0; c < 2; ++c) {
      int col = c * 16 + lrow;
      float g1 = gbuf[col * 3 + 1];
      float g2 = gbuf[col * 3 + 2];
      f32x4 a = acc2[r][c];
      float4 prev = *(float4*)&sAll[col * PADF + o];
      float pr[4] = {prev.x, prev.y, prev.z, prev.w};
      #pragma unroll
      for (int u = 0; u < 4; ++u) {
        float cv = gelu_f(a[u]);
        float sm = cv;
        sm += __shfl_xor(sm, 1);
        sm += __shfl_xor(sm, 2);
        sm += __shfl_xor(sm, 4);
        float gm = gelu_f(sm * 0.125f);
        pr[u] += cv * g1 + gm * g2;
      }
      *(float4*)&sAll[col * PADF + o] = make_float4(pr[0], pr[1], pr[2], pr[3]);
    }
  }
  __syncthreads();

  // ---- mod_t = Wht @ ctx_all + bht ----
  f32x4 acc3[3][2] = {};
  for (int kb = 0; kb < 6; ++kb) {
    int k0 = kb * 32;
    short8v ah[3], al[3], bh[2], bl[2];
    #pragma unroll
    for (int r = 0; r < 3; ++r) {
      size_t aoff = ((size_t)(m0 + r * 16 + lrow)) * 192 + k0 + lk;
      ah[r] = *(const short8v*)(WHh + aoff);
      al[r] = *(const short8v*)(WHl + aoff);
    }
    #pragma unroll
    for (int c = 0; c < 2; ++c) {
      int col = c * 16 + lrow;
      const float* p = &sAll[col * PADF + k0 + lk];
      float4 f0 = *(const float4*)p;
      float4 f1 = *(const float4*)(p + 4);
      float ff[8] = {f0.x, f0.y, f0.z, f0.w, f1.x, f1.y, f1.z, f1.w};
      short8v hv, lv;
      #pragma unroll
      for (int u = 0; u < 8; ++u) {
        u16 h = bf16hi(ff[u]);
        hv[u] = (short)h;
        lv[u] = (short)bf16hi(ff[u] - bf2f(h));
      }
      bh[c] = hv;
      bl[c] = lv;
    }
    #pragma unroll
    for (int r = 0; r < 3; ++r)
      #pragma unroll
      for (int c = 0; c < 2; ++c) {
        acc3[r][c] = __builtin_amdgcn_mfma_f32_16x16x32_bf16(ah[r], bh[c], acc3[r][c], 0, 0, 0);
        acc3[r][c] = __builtin_amdgcn_mfma_f32_16x16x32_bf16(ah[r], bl[c], acc3[r][c], 0, 0, 0);
        acc3[r][c] = __builtin_amdgcn_mfma_f32_16x16x32_bf16(al[r], bh[c], acc3[r][c], 0, 0, 0);
      }
  }

  // ---- store mod_t in SPATIAL token order ----
  #pragma unroll
  for (int r = 0; r < 3; ++r) {
    int o = m0 + r * 16 + orow;
    float4 bb4 = *(const float4*)&bht[o];
    #pragma unroll
    for (int c = 0; c < 2; ++c) {
      int col = c * 16 + lrow;
      int n = n0 + (col >> 3);
      int t = col & 7;
      int bg = n / PP;
      int hw = n - bg * PP;
      size_t tk = (size_t)(bg * 8 + t) * PP + hw;
      f32x4 a = acc3[r][c];
      *(float4*)&MT[tk * CC + o] =
          make_float4(a[0] + bb4.x, a[1] + bb4.y, a[2] + bb4.z, a[3] + bb4.w);
    }
  }
}

// ---------------- depthwise 3x3 + gelu (channel-last, float4 over c) ----------------
__global__ __launch_bounds__(256) void k_dw3(const float* __restrict__ IN,
    const float* __restrict__ fw, float* __restrict__ OUT)
{
  int idx = blockIdx.x * 256 + threadIdx.x;
  int tk = idx / 48;
  int cq = idx - tk * 48;
  if (tk >= NTOK) return;
  int c0 = cq << 2;
  int bb = tk / PP;
  int hw = tk - bb * PP;
  int h = hw / WWD;
  int w = hw - h * WWD;
  float wreg[9][4];
  #pragma unroll
  for (int kk = 0; kk < 9; ++kk) {
    #pragma unroll
    for (int u = 0; u < 4; ++u) wreg[kk][u] = fw[(c0 + u) * 9 + kk];
  }
  float a0 = 0.f, a1 = 0.f, a2 = 0.f, a3 = 0.f;
  const size_t rowbase = (size_t)bb * PP;
  #pragma unroll
  for (int kh = 0; kh < 3; ++kh) {
    int hh = h + kh - 1;
    if (hh < 0 || hh >= HH) continue;
    #pragma unroll
    for (int kw = 0; kw < 3; ++kw) {
      int wp = w + kw - 1;
      if (wp < 0 || wp >= WWD) continue;
      float4 v = *reinterpret_cast<const float4*>(IN + (rowbase + hh * WWD + wp) * CC + c0);
      int kk = kh * 3 + kw;
      a0 = fmaf(v.x, wreg[kk][0], a0);
      a1 = fmaf(v.y, wreg[kk][1], a1);
      a2 = fmaf(v.z, wreg[kk][2], a2);
      a3 = fmaf(v.w, wreg[kk][3], a3);
    }
  }
  float4 o;
  o.x = gelu_f(a0); o.y = gelu_f(a1); o.z = gelu_f(a2); o.w = gelu_f(a3);
  *reinterpret_cast<float4*>(OUT + (size_t)tk * CC + c0) = o;
}

// ---------------- depthwise 5x5 + gelu ----------------
__global__ __launch_bounds__(256) void k_dw5(const float* __restrict__ IN,
    const float* __restrict__ fw, float* __restrict__ OUT)
{
  int idx = blockIdx.x * 256 + threadIdx.x;
  int tk = idx / 48;
  int cq = idx - tk * 48;
  if (tk >= NTOK) return;
  int c0 = cq << 2;
  int bb = tk / PP;
  int hw = tk - bb * PP;
  int h = hw / WWD;
  int w = hw - h * WWD;
  float a0 = 0.f, a1 = 0.f, a2 = 0.f, a3 = 0.f;
  const size_t rowbase = (size_t)bb * PP;
  #pragma unroll
  for (int kh = 0; kh < 5; ++kh) {
    int hh = h + kh - 2;
    if (hh < 0 || hh >= HH) continue;
    #pragma unroll
    for (int kw = 0; kw < 5; ++kw) {
      int wp = w + kw - 2;
      if (wp < 0 || wp >= WWD) continue;
      float4 v = *reinterpret_cast<const float4*>(IN + (rowbase + hh * WWD + wp) * CC + c0);
      int kk = kh * 5 + kw;
      a0 = fmaf(v.x, fw[(c0 + 0) * 25 + kk], a0);
      a1 = fmaf(v.y, fw[(c0 + 1) * 25 + kk], a1);
      a2 = fmaf(v.z, fw[(c0 + 2) * 25 + kk], a2);
      a3 = fmaf(v.w, fw[(c0 + 3) * 25 + kk], a3);
    }
  }
  float4 o;
  o.x = gelu_f(a0); o.y = gelu_f(a1); o.z = gelu_f(a2); o.w = gelu_f(a3);
  *reinterpret_cast<float4*>(OUT + (size_t)tk * CC + c0) = o;
}

// ---------------- spatial global mean (two-pass, deterministic) ----------------
__global__ __launch_bounds__(192) void k_mean(const float* __restrict__ C2S,
                                              float* __restrict__ GMpart)
{
  int bb = blockIdx.x / 49;
  int chunk = blockIdx.x - bb * 49;
  int c = threadIdx.x;
  float s = 0.f;
  int hw0 = chunk * 64;
  const float* p = C2S + ((size_t)bb * PP + hw0) * CC + c;
  for (int i = 0; i < 64; ++i) s += p[(size_t)i * CC];
  GMpart[(size_t)chunk * 6144 + bb * CC + c] = s;
}

__global__ __launch_bounds__(256) void k_gmg(const float* __restrict__ GMpart,
                                             float* __restrict__ GMg)
{
  int i = blockIdx.x * 256 + threadIdx.x;
  if (i >= 6144) return;
  float s = 0.f;
  for (int p = 0; p < 49; ++p) s += GMpart[(size_t)p * 6144 + i];
  GMg[i] = gelu_f(s * (1.0f / 3136.0f));
}

// ---------------- mod GEMM: MOD = (c1*g0 + c2*g1 + gmean*g2) @ Wh^T + bh (in-place over C1) ----------------
__global__ __launch_bounds__(256) void k_mod(float* __restrict__ C1MOD,
    const float* __restrict__ C2S, const float* __restrict__ GS,
    const float* __restrict__ GMg, const float* __restrict__ WhT,
    const float* __restrict__ bh)
{
  __shared__ __align__(16) float As[32][68];
  __shared__ __align__(16) float Bs[32][200];
  const int tid = threadIdx.x;
  const int tx = tid & 15, ty = tid >> 4;
  const int row0 = blockIdx.x * 64;
  float acc[4][12] = {};
  for (int kb = 0; kb < 192; kb += 32) {
    {
      int m = tid >> 3;
      int kk = (tid & 7) << 2;
      #pragma unroll
      for (int it = 0; it < 2; ++it) {
        int mm = m + it * 32;
        int tk = row0 + mm;
        int bb = tk / PP;
        size_t base = (size_t)tk * CC + kb + kk;
        float4 v1 = *reinterpret_cast<const float4*>(C1MOD + base);
        float4 v2 = *reinterpret_cast<const float4*>(C2S + base);
        float4 vg = *reinterpret_cast<const float4*>(GMg + bb * CC + kb + kk);
        float g0 = GS[(size_t)tk * 3 + 0];
        float g1 = GS[(size_t)tk * 3 + 1];
        float g2 = GS[(size_t)tk * 3 + 2];
        As[kk + 0][mm] = v1.x * g0 + v2.x * g1 + vg.x * g2;
        As[kk + 1][mm] = v1.y * g0 + v2.y * g1 + vg.y * g2;
        As[kk + 2][mm] = v1.z * g0 + v2.z * g1 + vg.z * g2;
        As[kk + 3][mm] = v1.w * g0 + v2.w * g1 + vg.w * g2;
      }
      #pragma unroll
      for (int it = 0; it < 6; ++it) {
        int li = tid + it * 256;
        int kr = li / 48;
        int cq = (li - kr * 48) << 2;
        float4 wv = *reinterpret_cast<const float4*>(WhT + (size_t)(kb + kr) * CC + cq);
        Bs[kr][cq + 0] = wv.x; Bs[kr][cq + 1] = wv.y;
        Bs[kr][cq + 2] = wv.z; Bs[kr][cq + 3] = wv.w;
      }
    }
    __syncthreads();
    #pragma unroll
    for (int kk2 = 0; kk2 < 32; ++kk2) {
      float4 a = *reinterpret_cast<const float4*>(&As[kk2][ty << 2]);
      float av[4] = {a.x, a.y, a.z, a.w};
      #pragma unroll
      for (int s = 0; s < 3; ++s) {
        float4 b = *reinterpret_cast<const float4*>(&Bs[kk2][(tx << 2) + (s << 6)]);
        float bv[4] = {b.x, b.y, b.z, b.w};
        #pragma unroll
        for (int i = 0; i < 4; ++i) {
          #pragma unroll
          for (int j = 0; j < 4; ++j)
            acc[i][s * 4 + j] = fmaf(av[i], bv[j], acc[i][s * 4 + j]);
        }
      }
    }
    __syncthreads();
  }
  #pragma unroll
  for (int i = 0; i < 4; ++i) {
    int tk = row0 + (ty << 2) + i;
    #pragma unroll
    for (int s = 0; s < 3; ++s) {
      #pragma unroll
      for (int j = 0; j < 4; ++j) {
        int o = (tx << 2) + (s << 6) + j;
        C1MOD[(size_t)tk * CC + o] = acc[i][s * 4 + j] + bh[o];
      }
    }
  }
}

// ---------------- output GEMM: out = (q * mod * mod_t) @ Wp + bp (in-place over MT in d_out) ----------------
__global__ __launch_bounds__(256) void k_out(const float* __restrict__ QS,
    const float* __restrict__ MOD, float* MTout,
    const float* __restrict__ Wp, const float* __restrict__ bp)
{
  __shared__ __align__(16) float As[32][68];
  __shared__ __align__(16) float Bs[32][200];
  const int tid = threadIdx.x;
  const int tx = tid & 15, ty = tid >> 4;
  const int row0 = blockIdx.x * 64;
  float acc[4][12] = {};
  for (int kb = 0; kb < 192; kb += 32) {
    {
      int m = tid >> 3;
      int kk = (tid & 7) << 2;
      #pragma unroll
      for (int it = 0; it < 2; ++it) {
        int mm = m + it * 32;
        int tk = row0 + mm;
        size_t base = (size_t)tk * CC + kb + kk;
        float4 q  = *reinterpret_cast<const float4*>(QS + base);
        float4 md = *reinterpret_cast<const float4*>(MOD + base);
        float4 mt = *reinterpret_cast<const float4*>(MTout + base);
        As[kk + 0][mm] = q.x * md.x * mt.x;
        As[kk + 1][mm] = q.y * md.y * mt.y;
        As[kk + 2][mm] = q.z * md.z * mt.z;
        As[kk + 3][mm] = q.w * md.w * mt.w;
      }
      #pragma unroll
      for (int it = 0; it < 6; ++it) {
        int li = tid + it * 256;
        int kr = li / 48;
        int cq = (li - kr * 48) << 2;
        float4 wv = *reinterpret_cast<const float4*>(Wp + (size_t)(kb + kr) * CC + cq);
        Bs[kr][cq + 0] = wv.x; Bs[kr][cq + 1] = wv.y;
        Bs[kr][cq + 2] = wv.z; Bs[kr][cq + 3] = wv.w;
      }
    }
    __syncthreads();
    #pragma unroll
    for (int kk2 = 0; kk2 < 32; ++kk2) {
      float4 a = *reinterpret_cast<const float4*>(&As[kk2][ty << 2]);
      float av[4] = {a.x, a.y, a.z, a.w};
      #pragma unroll
      for (int s = 0; s < 3; ++s) {
        float4 b = *reinterpret_cast<const float4*>(&Bs[kk2][(tx << 2) + (s << 6)]);
        float bv[4] = {b.x, b.y, b.z, b.w};
        #pragma unroll
        for (int i = 0; i < 4; ++i) {
          #pragma unroll
          for (int j = 0; j < 4; ++j)
            acc[i][s * 4 + j] = fmaf(av[i], bv[j], acc[i][s * 4 + j]);
        }
      }
    }
    __syncthreads();
  }
  #pragma unroll
  for (int i = 0; i < 4; ++i) {
    int tk = row0 + (ty << 2) + i;
    #pragma unroll
    for (int s = 0; s < 3; ++s) {
      #pragma unroll
      for (int j = 0; j < 4; ++j) {
        int o = (tx << 2) + (s << 6) + j;
        MTout[(size_t)tk * CC + o] = acc[i][s * 4 + j] + bp[o];
      }
    }
  }
}

extern "C" void kernel_launch(void* const* d_in, const int* in_sizes, int n_in,
                              void* d_out, int out_size, void* d_ws, size_t ws_size,
                              hipStream_t stream)
{
  (void)in_sizes; (void)n_in; (void)out_size; (void)ws_size;
  const float* x   = (const float*)d_in[0];
  const float* Wf  = (const float*)d_in[1];
  const float* bf  = (const float*)d_in[2];
  const float* Wft = (const float*)d_in[3];
  const float* bft = (const float*)d_in[4];
  const float* fw0 = (const float*)d_in[5];
  const float* fw1 = (const float*)d_in[6];
  const float* tw0 = (const float*)d_in[7];
  const float* tw1 = (const float*)d_in[8];
  const float* Wh  = (const float*)d_in[9];
  const float* bh  = (const float*)d_in[10];
  const float* Wht = (const float*)d_in[11];
  const float* bht = (const float*)d_in[12];
  const float* Wp  = (const float*)d_in[13];
  const float* bp  = (const float*)d_in[14];

  float* ws = (float*)d_ws;
  const size_t SZ = (size_t)NTOK * CC;          // 19,267,584 floats (77 MB)
  float* QS     = ws + 0 * SZ;                  // q (spatial)
  float* WS1    = ws + 1 * SZ;                  // ctx_s -> c2_s
  float* WS2    = ws + 2 * SZ;                  // ctx_t -> c1_s -> MOD
  float* MT     = (float*)d_out;                // mod_t (SPATIAL order) -> out, in-place
  float* GS     = ws + 3 * SZ;                  // gates_s [tok][3]
  float* GT     = GS + (size_t)NTOK * 3;        // gates_t [n*8+t][3]
  float* GMpart = GT + (size_t)NTOK * 3;        // 49 x 6144 partial sums
  float* GMg    = GMpart + 49 * 6144;           // gelu(mean) [32][192]
  float* WhT    = GMg + 6144;                   // Wh^T (192 x 192) fp32 for k_mod
  u16* W3h = (u16*)(WhT + 192 * 192);           // conv3 weights [k][o][i] bf16 hi
  u16* W3l = W3h + 3 * 192 * 192;
  u16* W5h = W3l + 3 * 192 * 192;
  u16* W5l = W5h + 5 * 192 * 192;
  u16* WHh = W5l + 5 * 192 * 192;
  u16* WHl = WHh + 192 * 192;

  k_tw<<<144, 256, 0, stream>>>(Wh, WhT, 1);
  k_wsplit<<<432, 256, 0, stream>>>(tw0, W3h, W3l, 3);
  k_wsplit<<<720, 256, 0, stream>>>(tw1, W5h, W5l, 5);
  k_wsplit<<<144, 256, 0, stream>>>(Wht, WHh, WHl, 1);

  k_in<<<dim3(10, 1568), 256, 0, stream>>>(x, Wf, bf, Wft, bft, QS, WS1, GS, WS2, GT);
  k_t_mfma<<<3136, 256, 0, stream>>>(WS2, GT, W3h, W3l, W5h, W5l, WHh, WHl, bht, MT);

  k_dw3<<<18816, 256, 0, stream>>>(WS1, fw0, WS2);      // ctx -> c1 (over ctx_t)
  k_dw5<<<18816, 256, 0, stream>>>(WS2, fw1, WS1);      // c1  -> c2 (over ctx)
  k_mean<<<32 * 49, 192, 0, stream>>>(WS1, GMpart);
  k_gmg<<<24, 256, 0, stream>>>(GMpart, GMg);

  k_mod<<<1568, 256, 0, stream>>>(WS2, WS1, GS, GMg, WhT, bh);        // MOD over C1
  k_out<<<1568, 256, 0, stream>>>(QS, WS2, MT, Wp, bp);               // out over MT
}

// Round 4
// 1646.310 us; speedup vs baseline: 1.9354x; 1.0387x over previous
//
#include <hip/hip_runtime.h>
#include <math.h>

#define CC    192
#define TT    8
#define HH    56
#define WWD   56
#define PP    3136      // H*W
#define NTOK  100352    // 32*56*56
#define NSEQ  12544     // 4*56*56

typedef __attribute__((ext_vector_type(8))) short short8v;  // 8 bf16 (4 VGPR)
typedef __attribute__((ext_vector_type(4))) float f32x4;
using u16 = unsigned short;

__device__ __forceinline__ float gelu_f(float v) {
  return 0.5f * v * (1.0f + erff(v * 0.70710678f));
}

__device__ __forceinline__ u16 bf16hi(float f) {
  unsigned u = __builtin_bit_cast(unsigned, f);
  u += 0x7fffu + ((u >> 16) & 1u);
  return (u16)(u >> 16);
}
__device__ __forceinline__ float bf2f(u16 h) {
  unsigned u = ((unsigned)h) << 16;
  return __builtin_bit_cast(float, u);
}

__device__ __forceinline__ void split4(float4 v, uint2* ph, uint2* pl) {
  float vv[4] = {v.x, v.y, v.z, v.w};
  u16 hh[4], ll[4];
  #pragma unroll
  for (int u = 0; u < 4; ++u) {
    hh[u] = bf16hi(vv[u]);
    ll[u] = bf16hi(vv[u] - bf2f(hh[u]));
  }
  *ph = make_uint2((unsigned)hh[0] | ((unsigned)hh[1] << 16),
                   (unsigned)hh[2] | ((unsigned)hh[3] << 16));
  *pl = make_uint2((unsigned)ll[0] | ((unsigned)ll[1] << 16),
                   (unsigned)ll[2] | ((unsigned)ll[3] << 16));
}

// ---------------- weight split to bf16 hi/lo, layout [k][o][i] (temporal convs) ----------------
__global__ __launch_bounds__(256) void k_wsplit(const float* __restrict__ in,
    u16* __restrict__ hi, u16* __restrict__ lo, int K) {
  int idx = blockIdx.x * 256 + threadIdx.x;
  int total = CC * CC * K;
  if (idx >= total) return;
  int i = idx % CC;
  int rest = idx / CC;
  int o = rest % CC;
  int k = rest / CC;
  float f = in[(o * CC + i) * K + k];
  u16 h = bf16hi(f);
  hi[idx] = h;
  lo[idx] = bf16hi(f - bf2f(h));
}

// ---------------- combined input-proj weight: WI[j][k], j<768 (zero-padded) ----------------
__global__ __launch_bounds__(256) void k_wsplit_in(const float* __restrict__ Wf,
    const float* __restrict__ Wft, u16* __restrict__ hi, u16* __restrict__ lo) {
  int idx = blockIdx.x * 256 + threadIdx.x;
  if (idx >= 768 * CC) return;
  int k = idx % CC;
  int j = idx / CC;
  float f = 0.0f;
  if (j < 387) f = Wf[k * 387 + j];
  else if (j < 582) f = Wft[k * 195 + (j - 387)];
  u16 h = bf16hi(f);
  hi[idx] = h;
  lo[idx] = bf16hi(f - bf2f(h));
}

// ---------------- direct split (Wh: already [o][c]) ----------------
__global__ __launch_bounds__(256) void k_wsplit_d(const float* __restrict__ in,
    u16* __restrict__ hi, u16* __restrict__ lo) {
  int idx = blockIdx.x * 256 + threadIdx.x;
  if (idx >= CC * CC) return;
  float f = in[idx];
  u16 h = bf16hi(f);
  hi[idx] = h;
  lo[idx] = bf16hi(f - bf2f(h));
}

// ---------------- transpose split (Wp[c][o] -> [o][c]) ----------------
__global__ __launch_bounds__(256) void k_wsplit_t(const float* __restrict__ in,
    u16* __restrict__ hi, u16* __restrict__ lo) {
  int idx = blockIdx.x * 256 + threadIdx.x;
  if (idx >= CC * CC) return;
  int c = idx % CC;
  int o = idx / CC;
  float f = in[c * CC + o];
  u16 h = bf16hi(f);
  hi[idx] = h;
  lo[idx] = bf16hi(f - bf2f(h));
}

// ---------------- input projection, split-bf16 MFMA ----------------
// grid (3136, 2): 32 tokens x 384 j per block; wave w owns 96 j (6 rowtiles) x 2 coltiles.
__global__ __launch_bounds__(256, 2) void k_in_mfma(const float* __restrict__ x,
    const u16* __restrict__ WIh, const u16* __restrict__ WIl,
    const float* __restrict__ bf, const float* __restrict__ bft,
    float* __restrict__ QS, float* __restrict__ CS, float* __restrict__ GS,
    float* __restrict__ CT, float* __restrict__ GT)
{
  __shared__ __align__(16) u16 xh[32 * 200];
  __shared__ __align__(16) u16 xl[32 * 200];
  const int tid  = threadIdx.x;
  const int lane = tid & 63;
  const int w    = tid >> 6;
  const int lrow = lane & 15;
  const int lk   = (lane >> 4) * 8;
  const int orow = (lane >> 4) * 4;
  const int tk0  = blockIdx.x * 32;
  const int jw0  = blockIdx.y * 384 + w * 96;

  #pragma unroll
  for (int it = 0; it < 6; ++it) {
    int idx = tid + it * 256;                 // 0..1535
    int tokl = idx / 48;
    int c = (idx - tokl * 48) * 4;
    float4 v = *(const float4*)(x + (size_t)(tk0 + tokl) * CC + c);
    split4(v, (uint2*)&xh[tokl * 200 + c], (uint2*)&xl[tokl * 200 + c]);
  }
  __syncthreads();

  f32x4 acc[6][2] = {};
  #pragma unroll
  for (int kb = 0; kb < 6; ++kb) {
    int k0 = kb * 32;
    short8v ah[6], al[6], bh[2], bl[2];
    #pragma unroll
    for (int r = 0; r < 6; ++r) {
      size_t aoff = (size_t)(jw0 + r * 16 + lrow) * 192 + k0 + lk;
      ah[r] = *(const short8v*)(WIh + aoff);
      al[r] = *(const short8v*)(WIl + aoff);
    }
    #pragma unroll
    for (int c = 0; c < 2; ++c) {
      int tokl = c * 16 + lrow;
      bh[c] = *(const short8v*)&xh[tokl * 200 + k0 + lk];
      bl[c] = *(const short8v*)&xl[tokl * 200 + k0 + lk];
    }
    #pragma unroll
    for (int r = 0; r < 6; ++r)
      #pragma unroll
      for (int c = 0; c < 2; ++c) {
        acc[r][c] = __builtin_amdgcn_mfma_f32_16x16x32_bf16(ah[r], bh[c], acc[r][c], 0, 0, 0);
        acc[r][c] = __builtin_amdgcn_mfma_f32_16x16x32_bf16(ah[r], bl[c], acc[r][c], 0, 0, 0);
        acc[r][c] = __builtin_amdgcn_mfma_f32_16x16x32_bf16(al[r], bh[c], acc[r][c], 0, 0, 0);
      }
  }

  #pragma unroll
  for (int c = 0; c < 2; ++c) {
    int tok = tk0 + c * 16 + lrow;
    int bb = tok / PP;
    int hw = tok - bb * PP;
    size_t ctbase = ((size_t)((bb >> 3) * PP + hw) * 8 + (size_t)(bb & 7));
    #pragma unroll
    for (int r = 0; r < 6; ++r) {
      int jb = jw0 + r * 16 + orow;
      #pragma unroll
      for (int u = 0; u < 4; ++u) {
        int j = jb + u;
        if (j >= 582) continue;
        float bias = (j < 387) ? bf[j] : bft[j - 387];
        float val = acc[r][c][u] + bias;
        if (j < 192)      QS[(size_t)tok * CC + j] = val;
        else if (j < 384) CS[(size_t)tok * CC + (j - 192)] = val;
        else if (j < 387) GS[(size_t)tok * 3 + (j - 384)] = val;
        else if (j < 579) CT[ctbase * CC + (j - 387)] = val;
        else              GT[ctbase * 3 + (j - 579)] = val;
      }
    }
  }
}

// ---------------- temporal pipeline, split-bf16 MFMA ----------------
#define PADB 200
#define PADF 196
__global__ __launch_bounds__(256, 2) void k_t_mfma(
    const float* __restrict__ CT, const float* __restrict__ GT,
    const u16* __restrict__ W3h, const u16* __restrict__ W3l,
    const u16* __restrict__ W5h, const u16* __restrict__ W5l,
    const u16* __restrict__ WHh, const u16* __restrict__ WHl,
    const float* __restrict__ bht, float* __restrict__ MT)
{
  __shared__ __align__(16) u16 uA[2 * 48 * PADB];   // ctx hi|lo ; later sAll fp32 [32][PADF]
  __shared__ __align__(16) u16 uC[2 * 48 * PADB];   // c1 hi|lo
  __shared__ float gbuf[96];
  u16* ctxh = uA;
  u16* ctxl = uA + 48 * PADB;
  u16* c1h  = uC;
  u16* c1l  = uC + 48 * PADB;
  float* sAll = (float*)uA;                          // [32][PADF]

  const int tid  = threadIdx.x;
  const int lane = tid & 63;
  const int w    = tid >> 6;
  const int m0   = w * 48;
  const int lrow = lane & 15;
  const int lk   = (lane >> 4) * 8;
  const int orow = (lane >> 4) * 4;
  const int n0   = blockIdx.x * 4;

  if (tid < 96) gbuf[tid] = GT[(size_t)n0 * 24 + tid];

  for (int i = tid; i < 16 * 96; i += 256) {
    int hc = i / 96, j = i - hc * 96;
    int s = hc >> 2, which = hc & 3;
    int pc = s * 12 + ((which < 2) ? which : (8 + which));   // 0,1,10,11
    ((unsigned*)&ctxh[pc * PADB])[j] = 0u;
    ((unsigned*)&ctxl[pc * PADB])[j] = 0u;
    ((unsigned*)&c1h [pc * PADB])[j] = 0u;
    ((unsigned*)&c1l [pc * PADB])[j] = 0u;
  }

  {
    const float4* src = (const float4*)(CT + (size_t)n0 * 1536);
    #pragma unroll
    for (int it = 0; it < 6; ++it) {
      int idx = tid + it * 256;           // 0..1535 float4
      int e = idx * 4;
      int s = e / 1536;
      int r2 = e - s * 1536;
      int t = r2 / 192;
      int c = r2 - t * 192;
      float4 v = src[idx];
      int pc = s * 12 + 2 + t;
      split4(v, (uint2*)&ctxh[pc * PADB + c], (uint2*)&ctxl[pc * PADB + c]);
    }
  }
  __syncthreads();

  int pcolBase[2];
  #pragma unroll
  for (int c = 0; c < 2; ++c) {
    int col = c * 16 + lrow;
    pcolBase[c] = (col >> 3) * 12 + 2 + (col & 7);
  }

  // ---- conv K=3 ----
  f32x4 acc[3][2] = {};
  for (int off = 0; off < 3; ++off) {
    int sh = off - 1;
    #pragma unroll
    for (int kb = 0; kb < 6; ++kb) {
      int k0 = kb * 32;
      short8v ah[3], al[3], bh[2], bl[2];
      #pragma unroll
      for (int r = 0; r < 3; ++r) {
        size_t aoff = ((size_t)(off * 192 + m0 + r * 16 + lrow)) * 192 + k0 + lk;
        ah[r] = *(const short8v*)(W3h + aoff);
        al[r] = *(const short8v*)(W3l + aoff);
      }
      #pragma unroll
      for (int c = 0; c < 2; ++c) {
        int pc = pcolBase[c] + sh;
        bh[c] = *(const short8v*)&ctxh[pc * PADB + k0 + lk];
        bl[c] = *(const short8v*)&ctxl[pc * PADB + k0 + lk];
      }
      #pragma unroll
      for (int r = 0; r < 3; ++r)
        #pragma unroll
        for (int c = 0; c < 2; ++c) {
          acc[r][c] = __builtin_amdgcn_mfma_f32_16x16x32_bf16(ah[r], bh[c], acc[r][c], 0, 0, 0);
          acc[r][c] = __builtin_amdgcn_mfma_f32_16x16x32_bf16(ah[r], bl[c], acc[r][c], 0, 0, 0);
          acc[r][c] = __builtin_amdgcn_mfma_f32_16x16x32_bf16(al[r], bh[c], acc[r][c], 0, 0, 0);
        }
    }
  }
  __syncthreads();   // all ctx reads done before sAll overwrites uA

  #pragma unroll
  for (int r = 0; r < 3; ++r) {
    int o = m0 + r * 16 + orow;
    #pragma unroll
    for (int c = 0; c < 2; ++c) {
      int col = c * 16 + lrow;
      int pc = pcolBase[c];
      float g0 = gbuf[col * 3 + 0];
      f32x4 a = acc[r][c];
      u16 hh[4], ll[4];
      float cv[4];
      #pragma unroll
      for (int u = 0; u < 4; ++u) {
        float c1v = gelu_f(a[u]);
        hh[u] = bf16hi(c1v);
        ll[u] = bf16hi(c1v - bf2f(hh[u]));
        cv[u] = c1v * g0;
      }
      *(uint2*)&c1h[pc * PADB + o] =
          make_uint2((unsigned)hh[0] | ((unsigned)hh[1] << 16),
                     (unsigned)hh[2] | ((unsigned)hh[3] << 16));
      *(uint2*)&c1l[pc * PADB + o] =
          make_uint2((unsigned)ll[0] | ((unsigned)ll[1] << 16),
                     (unsigned)ll[2] | ((unsigned)ll[3] << 16));
      *(float4*)&sAll[col * PADF + o] = make_float4(cv[0], cv[1], cv[2], cv[3]);
    }
  }
  __syncthreads();

  // ---- conv K=5 ----
  f32x4 acc2[3][2] = {};
  for (int off = 0; off < 5; ++off) {
    int sh = off - 2;
    #pragma unroll
    for (int kb = 0; kb < 6; ++kb) {
      int k0 = kb * 32;
      short8v ah[3], al[3], bh[2], bl[2];
      #pragma unroll
      for (int r = 0; r < 3; ++r) {
        size_t aoff = ((size_t)(off * 192 + m0 + r * 16 + lrow)) * 192 + k0 + lk;
        ah[r] = *(const short8v*)(W5h + aoff);
        al[r] = *(const short8v*)(W5l + aoff);
      }
      #pragma unroll
      for (int c = 0; c < 2; ++c) {
        int pc = pcolBase[c] + sh;
        bh[c] = *(const short8v*)&c1h[pc * PADB + k0 + lk];
        bl[c] = *(const short8v*)&c1l[pc * PADB + k0 + lk];
      }
      #pragma unroll
      for (int r = 0; r < 3; ++r)
        #pragma unroll
        for (int c = 0; c < 2; ++c) {
          acc2[r][c] = __builtin_amdgcn_mfma_f32_16x16x32_bf16(ah[r], bh[c], acc2[r][c], 0, 0, 0);
          acc2[r][c] = __builtin_amdgcn_mfma_f32_16x16x32_bf16(ah[r], bl[c], acc2[r][c], 0, 0, 0);
          acc2[r][c] = __builtin_amdgcn_mfma_f32_16x16x32_bf16(al[r], bh[c], acc2[r][c], 0, 0, 0);
        }
    }
  }

  #pragma unroll
  for (int r = 0; r < 3; ++r) {
    int o = m0 + r * 16 + orow;
    #pragma unroll
    for (int c = 0; c < 2; ++c) {
      int col = c * 16 + lrow;
      float g1 = gbuf[col * 3 + 1];
      float g2 = gbuf[col * 3 + 2];
      f32x4 a = acc2[r][c];
      float4 prev = *(float4*)&sAll[col * PADF + o];
      float pr[4] = {prev.x, prev.y, prev.z, prev.w};
      #pragma unroll
      for (int u = 0; u < 4; ++u) {
        float cv = gelu_f(a[u]);
        float sm = cv;
        sm += __shfl_xor(sm, 1);
        sm += __shfl_xor(sm, 2);
        sm += __shfl_xor(sm, 4);
        float gm = gelu_f(sm * 0.125f);
        pr[u] += cv * g1 + gm * g2;
      }
      *(float4*)&sAll[col * PADF + o] = make_float4(pr[0], pr[1], pr[2], pr[3]);
    }
  }
  __syncthreads();

  // ---- mod_t = Wht @ ctx_all + bht ----
  f32x4 acc3[3][2] = {};
  #pragma unroll
  for (int kb = 0; kb < 6; ++kb) {
    int k0 = kb * 32;
    short8v ah[3], al[3], bh[2], bl[2];
    #pragma unroll
    for (int r = 0; r < 3; ++r) {
      size_t aoff = ((size_t)(m0 + r * 16 + lrow)) * 192 + k0 + lk;
      ah[r] = *(const short8v*)(WHh + aoff);
      al[r] = *(const short8v*)(WHl + aoff);
    }
    #pragma unroll
    for (int c = 0; c < 2; ++c) {
      int col = c * 16 + lrow;
      const float* p = &sAll[col * PADF + k0 + lk];
      float4 f0 = *(const float4*)p;
      float4 f1 = *(const float4*)(p + 4);
      float ff[8] = {f0.x, f0.y, f0.z, f0.w, f1.x, f1.y, f1.z, f1.w};
      short8v hv, lv;
      #pragma unroll
      for (int u = 0; u < 8; ++u) {
        u16 h = bf16hi(ff[u]);
        hv[u] = (short)h;
        lv[u] = (short)bf16hi(ff[u] - bf2f(h));
      }
      bh[c] = hv;
      bl[c] = lv;
    }
    #pragma unroll
    for (int r = 0; r < 3; ++r)
      #pragma unroll
      for (int c = 0; c < 2; ++c) {
        acc3[r][c] = __builtin_amdgcn_mfma_f32_16x16x32_bf16(ah[r], bh[c], acc3[r][c], 0, 0, 0);
        acc3[r][c] = __builtin_amdgcn_mfma_f32_16x16x32_bf16(ah[r], bl[c], acc3[r][c], 0, 0, 0);
        acc3[r][c] = __builtin_amdgcn_mfma_f32_16x16x32_bf16(al[r], bh[c], acc3[r][c], 0, 0, 0);
      }
  }

  #pragma unroll
  for (int r = 0; r < 3; ++r) {
    int o = m0 + r * 16 + orow;
    float4 bb4 = *(const float4*)&bht[o];
    #pragma unroll
    for (int c = 0; c < 2; ++c) {
      int col = c * 16 + lrow;
      int n = n0 + (col >> 3);
      int t = col & 7;
      int bg = n / PP;
      int hw = n - bg * PP;
      size_t tk = (size_t)(bg * 8 + t) * PP + hw;
      f32x4 a = acc3[r][c];
      *(float4*)&MT[tk * CC + o] =
          make_float4(a[0] + bb4.x, a[1] + bb4.y, a[2] + bb4.z, a[3] + bb4.w);
    }
  }
}

// ---------------- depthwise 3x3 + gelu ----------------
__global__ __launch_bounds__(256) void k_dw3(const float* __restrict__ IN,
    const float* __restrict__ fw, float* __restrict__ OUT)
{
  int idx = blockIdx.x * 256 + threadIdx.x;
  int tk = idx / 48;
  int cq = idx - tk * 48;
  if (tk >= NTOK) return;
  int c0 = cq << 2;
  int bb = tk / PP;
  int hw = tk - bb * PP;
  int h = hw / WWD;
  int w = hw - h * WWD;
  float wreg[9][4];
  #pragma unroll
  for (int kk = 0; kk < 9; ++kk) {
    #pragma unroll
    for (int u = 0; u < 4; ++u) wreg[kk][u] = fw[(c0 + u) * 9 + kk];
  }
  float a0 = 0.f, a1 = 0.f, a2 = 0.f, a3 = 0.f;
  const size_t rowbase = (size_t)bb * PP;
  #pragma unroll
  for (int kh = 0; kh < 3; ++kh) {
    int hh = h + kh - 1;
    if (hh < 0 || hh >= HH) continue;
    #pragma unroll
    for (int kw = 0; kw < 3; ++kw) {
      int wp = w + kw - 1;
      if (wp < 0 || wp >= WWD) continue;
      float4 v = *reinterpret_cast<const float4*>(IN + (rowbase + hh * WWD + wp) * CC + c0);
      int kk = kh * 3 + kw;
      a0 = fmaf(v.x, wreg[kk][0], a0);
      a1 = fmaf(v.y, wreg[kk][1], a1);
      a2 = fmaf(v.z, wreg[kk][2], a2);
      a3 = fmaf(v.w, wreg[kk][3], a3);
    }
  }
  float4 o;
  o.x = gelu_f(a0); o.y = gelu_f(a1); o.z = gelu_f(a2); o.w = gelu_f(a3);
  *reinterpret_cast<float4*>(OUT + (size_t)tk * CC + c0) = o;
}

// ---------------- depthwise 5x5 + gelu ----------------
__global__ __launch_bounds__(256) void k_dw5(const float* __restrict__ IN,
    const float* __restrict__ fw, float* __restrict__ OUT)
{
  int idx = blockIdx.x * 256 + threadIdx.x;
  int tk = idx / 48;
  int cq = idx - tk * 48;
  if (tk >= NTOK) return;
  int c0 = cq << 2;
  int bb = tk / PP;
  int hw = tk - bb * PP;
  int h = hw / WWD;
  int w = hw - h * WWD;
  float a0 = 0.f, a1 = 0.f, a2 = 0.f, a3 = 0.f;
  const size_t rowbase = (size_t)bb * PP;
  #pragma unroll
  for (int kh = 0; kh < 5; ++kh) {
    int hh = h + kh - 2;
    if (hh < 0 || hh >= HH) continue;
    #pragma unroll
    for (int kw = 0; kw < 5; ++kw) {
      int wp = w + kw - 2;
      if (wp < 0 || wp >= WWD) continue;
      float4 v = *reinterpret_cast<const float4*>(IN + (rowbase + hh * WWD + wp) * CC + c0);
      int kk = kh * 5 + kw;
      a0 = fmaf(v.x, fw[(c0 + 0) * 25 + kk], a0);
      a1 = fmaf(v.y, fw[(c0 + 1) * 25 + kk], a1);
      a2 = fmaf(v.z, fw[(c0 + 2) * 25 + kk], a2);
      a3 = fmaf(v.w, fw[(c0 + 3) * 25 + kk], a3);
    }
  }
  float4 o;
  o.x = gelu_f(a0); o.y = gelu_f(a1); o.z = gelu_f(a2); o.w = gelu_f(a3);
  *reinterpret_cast<float4*>(OUT + (size_t)tk * CC + c0) = o;
}

// ---------------- spatial global mean (two-pass) ----------------
__global__ __launch_bounds__(192) void k_mean(const float* __restrict__ C2S,
                                              float* __restrict__ GMpart)
{
  int bb = blockIdx.x / 49;
  int chunk = blockIdx.x - bb * 49;
  int c = threadIdx.x;
  float s = 0.f;
  int hw0 = chunk * 64;
  const float* p = C2S + ((size_t)bb * PP + hw0) * CC + c;
  for (int i = 0; i < 64; ++i) s += p[(size_t)i * CC];
  GMpart[(size_t)chunk * 6144 + bb * CC + c] = s;
}

__global__ __launch_bounds__(256) void k_gmg(const float* __restrict__ GMpart,
                                             float* __restrict__ GMg)
{
  int i = blockIdx.x * 256 + threadIdx.x;
  if (i >= 6144) return;
  float s = 0.f;
  for (int p = 0; p < 49; ++p) s += GMpart[(size_t)p * 6144 + i];
  GMg[i] = gelu_f(s * (1.0f / 3136.0f));
}

// ---------------- mod GEMM (split-bf16 MFMA), in-place over C1 ----------------
// grid 3136: 32 tokens/block; wave w owns 48 out (3 rowtiles) x 2 coltiles.
__global__ __launch_bounds__(256, 3) void k_mod_mfma(float* __restrict__ C1MOD,
    const float* __restrict__ C2S, const float* __restrict__ GS,
    const float* __restrict__ GMg,
    const u16* __restrict__ Wmh, const u16* __restrict__ Wml,
    const float* __restrict__ bh)
{
  __shared__ __align__(16) u16 sh_[32 * 200];
  __shared__ __align__(16) u16 sl_[32 * 200];
  const int tid  = threadIdx.x;
  const int lane = tid & 63;
  const int w    = tid >> 6;
  const int lrow = lane & 15;
  const int lk   = (lane >> 4) * 8;
  const int orow = (lane >> 4) * 4;
  const int tk0  = blockIdx.x * 32;
  const int m0   = w * 48;

  #pragma unroll
  for (int it = 0; it < 6; ++it) {
    int idx = tid + it * 256;
    int tokl = idx / 48;
    int c = (idx - tokl * 48) * 4;
    int tok = tk0 + tokl;
    int bb = tok / PP;
    size_t base = (size_t)tok * CC + c;
    float4 v1 = *(const float4*)(C1MOD + base);
    float4 v2 = *(const float4*)(C2S + base);
    float4 vg = *(const float4*)(GMg + bb * CC + c);
    float g0 = GS[(size_t)tok * 3 + 0];
    float g1 = GS[(size_t)tok * 3 + 1];
    float g2 = GS[(size_t)tok * 3 + 2];
    float4 av = make_float4(v1.x * g0 + v2.x * g1 + vg.x * g2,
                            v1.y * g0 + v2.y * g1 + vg.y * g2,
                            v1.z * g0 + v2.z * g1 + vg.z * g2,
                            v1.w * g0 + v2.w * g1 + vg.w * g2);
    split4(av, (uint2*)&sh_[tokl * 200 + c], (uint2*)&sl_[tokl * 200 + c]);
  }
  __syncthreads();

  f32x4 acc[3][2] = {};
  #pragma unroll
  for (int kb = 0; kb < 6; ++kb) {
    int k0 = kb * 32;
    short8v ah[3], al[3], bh4[2], bl4[2];
    #pragma unroll
    for (int r = 0; r < 3; ++r) {
      size_t aoff = (size_t)(m0 + r * 16 + lrow) * 192 + k0 + lk;
      ah[r] = *(const short8v*)(Wmh + aoff);
      al[r] = *(const short8v*)(Wml + aoff);
    }
    #pragma unroll
    for (int c = 0; c < 2; ++c) {
      int tokl = c * 16 + lrow;
      bh4[c] = *(const short8v*)&sh_[tokl * 200 + k0 + lk];
      bl4[c] = *(const short8v*)&sl_[tokl * 200 + k0 + lk];
    }
    #pragma unroll
    for (int r = 0; r < 3; ++r)
      #pragma unroll
      for (int c = 0; c < 2; ++c) {
        acc[r][c] = __builtin_amdgcn_mfma_f32_16x16x32_bf16(ah[r], bh4[c], acc[r][c], 0, 0, 0);
        acc[r][c] = __builtin_amdgcn_mfma_f32_16x16x32_bf16(ah[r], bl4[c], acc[r][c], 0, 0, 0);
        acc[r][c] = __builtin_amdgcn_mfma_f32_16x16x32_bf16(al[r], bh4[c], acc[r][c], 0, 0, 0);
      }
  }
  __syncthreads();   // all reads of C1MOD rows complete before in-place writes

  #pragma unroll
  for (int r = 0; r < 3; ++r) {
    int jb = m0 + r * 16 + orow;
    float4 b4 = *(const float4*)&bh[jb];
    #pragma unroll
    for (int c = 0; c < 2; ++c) {
      int tok = tk0 + c * 16 + lrow;
      f32x4 a = acc[r][c];
      *(float4*)&C1MOD[(size_t)tok * CC + jb] =
          make_float4(a[0] + b4.x, a[1] + b4.y, a[2] + b4.z, a[3] + b4.w);
    }
  }
}

// ---------------- output GEMM (split-bf16 MFMA), in-place over MT in d_out ----------------
__global__ __launch_bounds__(256, 3) void k_out_mfma(const float* __restrict__ QS,
    const float* __restrict__ MOD, float* MTout,
    const u16* __restrict__ Wph, const u16* __restrict__ Wpl,
    const float* __restrict__ bp)
{
  __shared__ __align__(16) u16 sh_[32 * 200];
  __shared__ __align__(16) u16 sl_[32 * 200];
  const int tid  = threadIdx.x;
  const int lane = tid & 63;
  const int w    = tid >> 6;
  const int lrow = lane & 15;
  const int lk   = (lane >> 4) * 8;
  const int orow = (lane >> 4) * 4;
  const int tk0  = blockIdx.x * 32;
  const int m0   = w * 48;

  #pragma unroll
  for (int it = 0; it < 6; ++it) {
    int idx = tid + it * 256;
    int tokl = idx / 48;
    int c = (idx - tokl * 48) * 4;
    size_t base = (size_t)(tk0 + tokl) * CC + c;
    float4 q  = *(const float4*)(QS + base);
    float4 md = *(const float4*)(MOD + base);
    float4 mt = *(const float4*)(MTout + base);
    float4 av = make_float4(q.x * md.x * mt.x, q.y * md.y * mt.y,
                            q.z * md.z * mt.z, q.w * md.w * mt.w);
    split4(av, (uint2*)&sh_[tokl * 200 + c], (uint2*)&sl_[tokl * 200 + c]);
  }
  __syncthreads();

  f32x4 acc[3][2] = {};
  #pragma unroll
  for (int kb = 0; kb < 6; ++kb) {
    int k0 = kb * 32;
    short8v ah[3], al[3], bh4[2], bl4[2];
    #pragma unroll
    for (int r = 0; r < 3; ++r) {
      size_t aoff = (size_t)(m0 + r * 16 + lrow) * 192 + k0 + lk;
      ah[r] = *(const short8v*)(Wph + aoff);
      al[r] = *(const short8v*)(Wpl + aoff);
    }
    #pragma unroll
    for (int c = 0; c < 2; ++c) {
      int tokl = c * 16 + lrow;
      bh4[c] = *(const short8v*)&sh_[tokl * 200 + k0 + lk];
      bl4[c] = *(const short8v*)&sl_[tokl * 200 + k0 + lk];
    }
    #pragma unroll
    for (int r = 0; r < 3; ++r)
      #pragma unroll
      for (int c = 0; c < 2; ++c) {
        acc[r][c] = __builtin_amdgcn_mfma_f32_16x16x32_bf16(ah[r], bh4[c], acc[r][c], 0, 0, 0);
        acc[r][c] = __builtin_amdgcn_mfma_f32_16x16x32_bf16(ah[r], bl4[c], acc[r][c], 0, 0, 0);
        acc[r][c] = __builtin_amdgcn_mfma_f32_16x16x32_bf16(al[r], bh4[c], acc[r][c], 0, 0, 0);
      }
  }
  __syncthreads();   // all MT reads complete before in-place writes

  #pragma unroll
  for (int r = 0; r < 3; ++r) {
    int jb = m0 + r * 16 + orow;
    float4 b4 = *(const float4*)&bp[jb];
    #pragma unroll
    for (int c = 0; c < 2; ++c) {
      int tok = tk0 + c * 16 + lrow;
      f32x4 a = acc[r][c];
      *(float4*)&MTout[(size_t)tok * CC + jb] =
          make_float4(a[0] + b4.x, a[1] + b4.y, a[2] + b4.z, a[3] + b4.w);
    }
  }
}

extern "C" void kernel_launch(void* const* d_in, const int* in_sizes, int n_in,
                              void* d_out, int out_size, void* d_ws, size_t ws_size,
                              hipStream_t stream)
{
  (void)in_sizes; (void)n_in; (void)out_size; (void)ws_size;
  const float* x   = (const float*)d_in[0];
  const float* Wf  = (const float*)d_in[1];
  const float* bf  = (const float*)d_in[2];
  const float* Wft = (const float*)d_in[3];
  const float* bft = (const float*)d_in[4];
  const float* fw0 = (const float*)d_in[5];
  const float* fw1 = (const float*)d_in[6];
  const float* tw0 = (const float*)d_in[7];
  const float* tw1 = (const float*)d_in[8];
  const float* Wh  = (const float*)d_in[9];
  const float* bh  = (const float*)d_in[10];
  const float* Wht = (const float*)d_in[11];
  const float* bht = (const float*)d_in[12];
  const float* Wp  = (const float*)d_in[13];
  const float* bp  = (const float*)d_in[14];

  float* ws = (float*)d_ws;
  const size_t SZ = (size_t)NTOK * CC;          // 19,267,584 floats (77 MB)
  float* QS     = ws + 0 * SZ;                  // q (spatial)
  float* WS1    = ws + 1 * SZ;                  // ctx_s -> c2_s
  float* WS2    = ws + 2 * SZ;                  // ctx_t -> c1_s -> MOD
  float* MT     = (float*)d_out;                // mod_t (spatial order) -> out, in-place
  float* GS     = ws + 3 * SZ;                  // gates_s [tok][3]
  float* GT     = GS + (size_t)NTOK * 3;        // gates_t [n*8+t][3]
  float* GMpart = GT + (size_t)NTOK * 3;        // 49 x 6144
  float* GMg    = GMpart + 49 * 6144;           // gelu(mean) [32][192]
  u16* W3h = (u16*)(GMg + 6144);                // conv3 [k][o][i] hi
  u16* W3l = W3h + 3 * 36864;
  u16* W5h = W3l + 3 * 36864;
  u16* W5l = W5h + 5 * 36864;
  u16* WHh = W5l + 5 * 36864;
  u16* WHl = WHh + 36864;
  u16* WIh = WHl + 36864;                       // input proj [j<768][k]
  u16* WIl = WIh + 768 * 192;
  u16* Wmh = WIl + 768 * 192;                   // Wh [o][c]
  u16* Wml = Wmh + 36864;
  u16* Wph = Wml + 36864;                       // Wp^T [o][c]
  u16* Wpl = Wph + 36864;

  k_wsplit<<<432, 256, 0, stream>>>(tw0, W3h, W3l, 3);
  k_wsplit<<<720, 256, 0, stream>>>(tw1, W5h, W5l, 5);
  k_wsplit<<<144, 256, 0, stream>>>(Wht, WHh, WHl, 1);
  k_wsplit_in<<<576, 256, 0, stream>>>(Wf, Wft, WIh, WIl);
  k_wsplit_d<<<144, 256, 0, stream>>>(Wh, Wmh, Wml);
  k_wsplit_t<<<144, 256, 0, stream>>>(Wp, Wph, Wpl);

  k_in_mfma<<<dim3(3136, 2), 256, 0, stream>>>(x, WIh, WIl, bf, bft,
                                               QS, WS1, GS, WS2, GT);
  k_t_mfma<<<3136, 256, 0, stream>>>(WS2, GT, W3h, W3l, W5h, W5l, WHh, WHl, bht, MT);

  k_dw3<<<18816, 256, 0, stream>>>(WS1, fw0, WS2);      // ctx -> c1 (over ctx_t)
  k_dw5<<<18816, 256, 0, stream>>>(WS2, fw1, WS1);      // c1  -> c2 (over ctx)
  k_mean<<<32 * 49, 192, 0, stream>>>(WS1, GMpart);
  k_gmg<<<24, 256, 0, stream>>>(GMpart, GMg);

  k_mod_mfma<<<3136, 256, 0, stream>>>(WS2, WS1, GS, GMg, Wmh, Wml, bh);   // MOD over C1
  k_out_mfma<<<3136, 256, 0, stream>>>(QS, WS2, MT, Wph, Wpl, bp);         // out over MT
}

// Round 5
// 1606.020 us; speedup vs baseline: 1.9839x; 1.0251x over previous
//
#include <hip/hip_runtime.h>
#include <math.h>

#define CC    192
#define TT    8
#define HH    56
#define WWD   56
#define PP    3136      // H*W
#define NTOK  100352    // 32*56*56
#define NSEQ  12544     // 4*56*56

typedef __attribute__((ext_vector_type(8))) short short8v;  // 8 bf16 (4 VGPR)
typedef __attribute__((ext_vector_type(4))) float f32x4;
using u16 = unsigned short;

__device__ __forceinline__ float gelu_f(float v) {
  return 0.5f * v * (1.0f + erff(v * 0.70710678f));
}

__device__ __forceinline__ u16 bf16hi(float f) {
  unsigned u = __builtin_bit_cast(unsigned, f);
  u += 0x7fffu + ((u >> 16) & 1u);
  return (u16)(u >> 16);
}
__device__ __forceinline__ float bf2f(u16 h) {
  unsigned u = ((unsigned)h) << 16;
  return __builtin_bit_cast(float, u);
}

__device__ __forceinline__ void split4(float4 v, uint2* ph, uint2* pl) {
  float vv[4] = {v.x, v.y, v.z, v.w};
  u16 hh[4], ll[4];
  #pragma unroll
  for (int u = 0; u < 4; ++u) {
    hh[u] = bf16hi(vv[u]);
    ll[u] = bf16hi(vv[u] - bf2f(hh[u]));
  }
  *ph = make_uint2((unsigned)hh[0] | ((unsigned)hh[1] << 16),
                   (unsigned)hh[2] | ((unsigned)hh[3] << 16));
  *pl = make_uint2((unsigned)ll[0] | ((unsigned)ll[1] << 16),
                   (unsigned)ll[2] | ((unsigned)ll[3] << 16));
}

// ---------------- weight split kernels ----------------
__global__ __launch_bounds__(256) void k_wsplit(const float* __restrict__ in,
    u16* __restrict__ hi, u16* __restrict__ lo, int K) {
  int idx = blockIdx.x * 256 + threadIdx.x;
  int total = CC * CC * K;
  if (idx >= total) return;
  int i = idx % CC;
  int rest = idx / CC;
  int o = rest % CC;
  int k = rest / CC;
  float f = in[(o * CC + i) * K + k];
  u16 h = bf16hi(f);
  hi[idx] = h;
  lo[idx] = bf16hi(f - bf2f(h));
}

__global__ __launch_bounds__(256) void k_wsplit_in(const float* __restrict__ Wf,
    const float* __restrict__ Wft, u16* __restrict__ hi, u16* __restrict__ lo) {
  int idx = blockIdx.x * 256 + threadIdx.x;
  if (idx >= 768 * CC) return;
  int k = idx % CC;
  int j = idx / CC;
  float f = 0.0f;
  if (j < 387) f = Wf[k * 387 + j];
  else if (j < 582) f = Wft[k * 195 + (j - 387)];
  u16 h = bf16hi(f);
  hi[idx] = h;
  lo[idx] = bf16hi(f - bf2f(h));
}

__global__ __launch_bounds__(256) void k_wsplit_d(const float* __restrict__ in,
    u16* __restrict__ hi, u16* __restrict__ lo) {
  int idx = blockIdx.x * 256 + threadIdx.x;
  if (idx >= CC * CC) return;
  float f = in[idx];
  u16 h = bf16hi(f);
  hi[idx] = h;
  lo[idx] = bf16hi(f - bf2f(h));
}

__global__ __launch_bounds__(256) void k_wsplit_t(const float* __restrict__ in,
    u16* __restrict__ hi, u16* __restrict__ lo) {
  int idx = blockIdx.x * 256 + threadIdx.x;
  if (idx >= CC * CC) return;
  int c = idx % CC;
  int o = idx / CC;
  float f = in[c * CC + o];
  u16 h = bf16hi(f);
  hi[idx] = h;
  lo[idx] = bf16hi(f - bf2f(h));
}

// ================= input projection, pipelined split-bf16 MFMA =================
// grid (3136,2): 32 tokens x 320 j per block; wave w owns 80 j (5 rowtiles) x 2 coltiles.
__global__ __launch_bounds__(256, 2) void k_in_mfma(const float* __restrict__ x,
    const u16* __restrict__ WIh, const u16* __restrict__ WIl,
    const float* __restrict__ bf, const float* __restrict__ bft,
    float* __restrict__ QS, float* __restrict__ CS, float* __restrict__ GS,
    float* __restrict__ CT, float* __restrict__ GT)
{
  __shared__ __align__(16) u16 xh[32 * 200];
  __shared__ __align__(16) u16 xl[32 * 200];
  const int tid  = threadIdx.x;
  const int lane = tid & 63;
  const int w    = tid >> 6;
  const int lrow = lane & 15;
  const int lk   = (lane >> 4) * 8;
  const int orow = (lane >> 4) * 4;
  const int tk0  = blockIdx.x * 32;
  const int jw0  = blockIdx.y * 320 + w * 80;

  #pragma unroll
  for (int it = 0; it < 6; ++it) {
    int idx = tid + it * 256;                 // 0..1535
    int tokl = idx / 48;
    int c = (idx - tokl * 48) * 4;
    float4 v = *(const float4*)(x + (size_t)(tk0 + tokl) * CC + c);
    split4(v, (uint2*)&xh[tokl * 200 + c], (uint2*)&xl[tokl * 200 + c]);
  }
  __syncthreads();

#define LOADA_IN(KB, AH, AL) { \
    _Pragma("unroll") for (int r = 0; r < 5; ++r) { \
      size_t aoff = (size_t)(jw0 + r * 16 + lrow) * 192 + (KB) * 32 + lk; \
      AH[r] = *(const short8v*)(WIh + aoff); \
      AL[r] = *(const short8v*)(WIl + aoff); } }
#define LOADB_IN(KB, BH, BL) { \
    _Pragma("unroll") for (int c = 0; c < 2; ++c) { \
      int tokl = c * 16 + lrow; \
      BH[c] = *(const short8v*)&xh[tokl * 200 + (KB) * 32 + lk]; \
      BL[c] = *(const short8v*)&xl[tokl * 200 + (KB) * 32 + lk]; } }

  f32x4 acc[5][2] = {};
  short8v ahb[2][5], alb[2][5], bhb[2][2], blb[2][2];
  LOADA_IN(0, ahb[0], alb[0]);
  LOADB_IN(0, bhb[0], blb[0]);
  #pragma unroll
  for (int kb = 0; kb < 6; ++kb) {
    const int cur = kb & 1, nxt = cur ^ 1;
    if (kb + 1 < 6) {
      LOADA_IN(kb + 1, ahb[nxt], alb[nxt]);
      LOADB_IN(kb + 1, bhb[nxt], blb[nxt]);
    }
    #pragma unroll
    for (int r = 0; r < 5; ++r)
      #pragma unroll
      for (int c = 0; c < 2; ++c) {
        acc[r][c] = __builtin_amdgcn_mfma_f32_16x16x32_bf16(ahb[cur][r], bhb[cur][c], acc[r][c], 0, 0, 0);
        acc[r][c] = __builtin_amdgcn_mfma_f32_16x16x32_bf16(ahb[cur][r], blb[cur][c], acc[r][c], 0, 0, 0);
        acc[r][c] = __builtin_amdgcn_mfma_f32_16x16x32_bf16(alb[cur][r], bhb[cur][c], acc[r][c], 0, 0, 0);
      }
  }
#undef LOADA_IN
#undef LOADB_IN

  #pragma unroll
  for (int c = 0; c < 2; ++c) {
    int tok = tk0 + c * 16 + lrow;
    int bb = tok / PP;
    int hw = tok - bb * PP;
    size_t ctbase = ((size_t)((bb >> 3) * PP + hw) * 8 + (size_t)(bb & 7));
    #pragma unroll
    for (int r = 0; r < 5; ++r) {
      int jb = jw0 + r * 16 + orow;
      #pragma unroll
      for (int u = 0; u < 4; ++u) {
        int j = jb + u;
        if (j >= 582) continue;
        float bias = (j < 387) ? bf[j] : bft[j - 387];
        float val = acc[r][c][u] + bias;
        if (j < 192)      QS[(size_t)tok * CC + j] = val;
        else if (j < 384) CS[(size_t)tok * CC + (j - 192)] = val;
        else if (j < 387) GS[(size_t)tok * 3 + (j - 384)] = val;
        else if (j < 579) CT[ctbase * CC + (j - 387)] = val;
        else              GT[ctbase * 3 + (j - 579)] = val;
      }
    }
  }
}

// ================= temporal pipeline, pipelined split-bf16 MFMA =================
#define PADB 200
#define PADF 196
__global__ __launch_bounds__(256, 2) void k_t_mfma(
    const float* __restrict__ CT, const float* __restrict__ GT,
    const u16* __restrict__ W3h, const u16* __restrict__ W3l,
    const u16* __restrict__ W5h, const u16* __restrict__ W5l,
    const u16* __restrict__ WHh, const u16* __restrict__ WHl,
    const float* __restrict__ bht, float* __restrict__ MT)
{
  __shared__ __align__(16) u16 uA[2 * 48 * PADB];   // ctx hi|lo ; later sAll fp32 [32][PADF]
  __shared__ __align__(16) u16 uC[2 * 48 * PADB];   // c1 hi|lo
  __shared__ float gbuf[96];
  u16* ctxh = uA;
  u16* ctxl = uA + 48 * PADB;
  u16* c1h  = uC;
  u16* c1l  = uC + 48 * PADB;
  float* sAll = (float*)uA;                          // [32][PADF]

  const int tid  = threadIdx.x;
  const int lane = tid & 63;
  const int w    = tid >> 6;
  const int m0   = w * 48;
  const int lrow = lane & 15;
  const int lk   = (lane >> 4) * 8;
  const int orow = (lane >> 4) * 4;
  const int n0   = blockIdx.x * 4;

  if (tid < 96) gbuf[tid] = GT[(size_t)n0 * 24 + tid];

  for (int i = tid; i < 16 * 96; i += 256) {
    int hc = i / 96, j = i - hc * 96;
    int s = hc >> 2, which = hc & 3;
    int pc = s * 12 + ((which < 2) ? which : (8 + which));   // 0,1,10,11
    ((unsigned*)&ctxh[pc * PADB])[j] = 0u;
    ((unsigned*)&ctxl[pc * PADB])[j] = 0u;
    ((unsigned*)&c1h [pc * PADB])[j] = 0u;
    ((unsigned*)&c1l [pc * PADB])[j] = 0u;
  }

  {
    const float4* src = (const float4*)(CT + (size_t)n0 * 1536);
    #pragma unroll
    for (int it = 0; it < 6; ++it) {
      int idx = tid + it * 256;           // 0..1535 float4
      int e = idx * 4;
      int s = e / 1536;
      int r2 = e - s * 1536;
      int t = r2 / 192;
      int c = r2 - t * 192;
      float4 v = src[idx];
      int pc = s * 12 + 2 + t;
      split4(v, (uint2*)&ctxh[pc * PADB + c], (uint2*)&ctxl[pc * PADB + c]);
    }
  }
  __syncthreads();

  int pcolBase[2];
  #pragma unroll
  for (int c = 0; c < 2; ++c) {
    int col = c * 16 + lrow;
    pcolBase[c] = (col >> 3) * 12 + 2 + (col & 7);
  }

#define LOADA_T(WH, WL, OFF, KB, AH, AL) { \
    _Pragma("unroll") for (int r = 0; r < 3; ++r) { \
      size_t aoff = ((size_t)((OFF) * 192 + m0 + r * 16 + lrow)) * 192 + (KB) * 32 + lk; \
      AH[r] = *(const short8v*)(WH + aoff); \
      AL[r] = *(const short8v*)(WL + aoff); } }
#define LOADB_T(SRCH, SRCL, SH, KB, BH, BL) { \
    _Pragma("unroll") for (int c = 0; c < 2; ++c) { \
      int pc = pcolBase[c] + (SH); \
      BH[c] = *(const short8v*)&SRCH[pc * PADB + (KB) * 32 + lk]; \
      BL[c] = *(const short8v*)&SRCL[pc * PADB + (KB) * 32 + lk]; } }
#define MFMA6(AH, AL, BH, BL, ACC) { \
    _Pragma("unroll") for (int r = 0; r < 3; ++r) \
      _Pragma("unroll") for (int c = 0; c < 2; ++c) { \
        ACC[r][c] = __builtin_amdgcn_mfma_f32_16x16x32_bf16(AH[r], BH[c], ACC[r][c], 0, 0, 0); \
        ACC[r][c] = __builtin_amdgcn_mfma_f32_16x16x32_bf16(AH[r], BL[c], ACC[r][c], 0, 0, 0); \
        ACC[r][c] = __builtin_amdgcn_mfma_f32_16x16x32_bf16(AL[r], BH[c], ACC[r][c], 0, 0, 0); } }

  short8v ahb[2][3], alb[2][3], bhb[2][2], blb[2][2];

  // ---- conv K=3 : 18 pipelined iterations (off = it/6, kb = it%6) ----
  f32x4 acc[3][2] = {};
  LOADA_T(W3h, W3l, 0, 0, ahb[0], alb[0]);
  LOADB_T(ctxh, ctxl, -1, 0, bhb[0], blb[0]);
  #pragma unroll
  for (int it = 0; it < 18; ++it) {
    const int cur = it & 1, nxt = cur ^ 1;
    if (it + 1 < 18) {
      const int no = (it + 1) / 6, nk = (it + 1) % 6;
      LOADA_T(W3h, W3l, no, nk, ahb[nxt], alb[nxt]);
      LOADB_T(ctxh, ctxl, no - 1, nk, bhb[nxt], blb[nxt]);
    }
    MFMA6(ahb[cur], alb[cur], bhb[cur], blb[cur], acc);
  }
  __syncthreads();   // all ctx reads done before sAll overwrites uA

  // ---- conv3 epilogue: c1 -> uC (hi/lo) ; sAll = c1*g0 ----
  #pragma unroll
  for (int r = 0; r < 3; ++r) {
    int o = m0 + r * 16 + orow;
    #pragma unroll
    for (int c = 0; c < 2; ++c) {
      int col = c * 16 + lrow;
      int pc = pcolBase[c];
      float g0 = gbuf[col * 3 + 0];
      f32x4 a = acc[r][c];
      u16 hh[4], ll[4];
      float cv[4];
      #pragma unroll
      for (int u = 0; u < 4; ++u) {
        float c1v = gelu_f(a[u]);
        hh[u] = bf16hi(c1v);
        ll[u] = bf16hi(c1v - bf2f(hh[u]));
        cv[u] = c1v * g0;
      }
      *(uint2*)&c1h[pc * PADB + o] =
          make_uint2((unsigned)hh[0] | ((unsigned)hh[1] << 16),
                     (unsigned)hh[2] | ((unsigned)hh[3] << 16));
      *(uint2*)&c1l[pc * PADB + o] =
          make_uint2((unsigned)ll[0] | ((unsigned)ll[1] << 16),
                     (unsigned)ll[2] | ((unsigned)ll[3] << 16));
      *(float4*)&sAll[col * PADF + o] = make_float4(cv[0], cv[1], cv[2], cv[3]);
    }
  }
  __syncthreads();

  // ---- conv K=5 : 30 pipelined iterations ----
  f32x4 acc2[3][2] = {};
  LOADA_T(W5h, W5l, 0, 0, ahb[0], alb[0]);
  LOADB_T(c1h, c1l, -2, 0, bhb[0], blb[0]);
  #pragma unroll
  for (int it = 0; it < 30; ++it) {
    const int cur = it & 1, nxt = cur ^ 1;
    if (it + 1 < 30) {
      const int no = (it + 1) / 6, nk = (it + 1) % 6;
      LOADA_T(W5h, W5l, no, nk, ahb[nxt], alb[nxt]);
      LOADB_T(c1h, c1l, no - 2, nk, bhb[nxt], blb[nxt]);
    }
    MFMA6(ahb[cur], alb[cur], bhb[cur], blb[cur], acc2);
  }

  // ---- conv5 epilogue: c2; temporal mean; sAll += c2*g1 + gm*g2 ----
  #pragma unroll
  for (int r = 0; r < 3; ++r) {
    int o = m0 + r * 16 + orow;
    #pragma unroll
    for (int c = 0; c < 2; ++c) {
      int col = c * 16 + lrow;
      float g1 = gbuf[col * 3 + 1];
      float g2 = gbuf[col * 3 + 2];
      f32x4 a = acc2[r][c];
      float4 prev = *(float4*)&sAll[col * PADF + o];
      float pr[4] = {prev.x, prev.y, prev.z, prev.w};
      #pragma unroll
      for (int u = 0; u < 4; ++u) {
        float cv = gelu_f(a[u]);
        float sm = cv;
        sm += __shfl_xor(sm, 1);
        sm += __shfl_xor(sm, 2);
        sm += __shfl_xor(sm, 4);
        float gm = gelu_f(sm * 0.125f);
        pr[u] += cv * g1 + gm * g2;
      }
      *(float4*)&sAll[col * PADF + o] = make_float4(pr[0], pr[1], pr[2], pr[3]);
    }
  }
  __syncthreads();

  // ---- mod_t = Wht @ ctx_all + bht (pipelined A loads + raw-B prefetch) ----
  f32x4 acc3[3][2] = {};
  float4 rb[2][4];
  LOADA_T(WHh, WHl, 0, 0, ahb[0], alb[0]);
  #pragma unroll
  for (int c = 0; c < 2; ++c) {
    const float* p = &sAll[(c * 16 + lrow) * PADF + lk];
    rb[0][c * 2 + 0] = *(const float4*)p;
    rb[0][c * 2 + 1] = *(const float4*)(p + 4);
  }
  #pragma unroll
  for (int kb = 0; kb < 6; ++kb) {
    const int cur = kb & 1, nxt = cur ^ 1;
    if (kb + 1 < 6) {
      LOADA_T(WHh, WHl, 0, kb + 1, ahb[nxt], alb[nxt]);
      #pragma unroll
      for (int c = 0; c < 2; ++c) {
        const float* p = &sAll[(c * 16 + lrow) * PADF + (kb + 1) * 32 + lk];
        rb[nxt][c * 2 + 0] = *(const float4*)p;
        rb[nxt][c * 2 + 1] = *(const float4*)(p + 4);
      }
    }
    #pragma unroll
    for (int c = 0; c < 2; ++c) {
      float4 f0 = rb[cur][c * 2 + 0];
      float4 f1 = rb[cur][c * 2 + 1];
      float ff[8] = {f0.x, f0.y, f0.z, f0.w, f1.x, f1.y, f1.z, f1.w};
      short8v hv, lv;
      #pragma unroll
      for (int u = 0; u < 8; ++u) {
        u16 h = bf16hi(ff[u]);
        hv[u] = (short)h;
        lv[u] = (short)bf16hi(ff[u] - bf2f(h));
      }
      bhb[cur][c] = hv;
      blb[cur][c] = lv;
    }
    #pragma unroll
    for (int r = 0; r < 3; ++r)
      #pragma unroll
      for (int c = 0; c < 2; ++c) {
        acc3[r][c] = __builtin_amdgcn_mfma_f32_16x16x32_bf16(ahb[cur][r], bhb[cur][c], acc3[r][c], 0, 0, 0);
        acc3[r][c] = __builtin_amdgcn_mfma_f32_16x16x32_bf16(ahb[cur][r], blb[cur][c], acc3[r][c], 0, 0, 0);
        acc3[r][c] = __builtin_amdgcn_mfma_f32_16x16x32_bf16(alb[cur][r], bhb[cur][c], acc3[r][c], 0, 0, 0);
      }
  }
#undef LOADA_T
#undef LOADB_T
#undef MFMA6

  #pragma unroll
  for (int r = 0; r < 3; ++r) {
    int o = m0 + r * 16 + orow;
    float4 bb4 = *(const float4*)&bht[o];
    #pragma unroll
    for (int c = 0; c < 2; ++c) {
      int col = c * 16 + lrow;
      int n = n0 + (col >> 3);
      int t = col & 7;
      int bg = n / PP;
      int hw = n - bg * PP;
      size_t tk = (size_t)(bg * 8 + t) * PP + hw;
      f32x4 a = acc3[r][c];
      *(float4*)&MT[tk * CC + o] =
          make_float4(a[0] + bb4.x, a[1] + bb4.y, a[2] + bb4.z, a[3] + bb4.w);
    }
  }
}

// ---------------- depthwise 3x3 + gelu ----------------
__global__ __launch_bounds__(256) void k_dw3(const float* __restrict__ IN,
    const float* __restrict__ fw, float* __restrict__ OUT)
{
  int idx = blockIdx.x * 256 + threadIdx.x;
  int tk = idx / 48;
  int cq = idx - tk * 48;
  if (tk >= NTOK) return;
  int c0 = cq << 2;
  int bb = tk / PP;
  int hw = tk - bb * PP;
  int h = hw / WWD;
  int w = hw - h * WWD;
  float wreg[9][4];
  #pragma unroll
  for (int kk = 0; kk < 9; ++kk) {
    #pragma unroll
    for (int u = 0; u < 4; ++u) wreg[kk][u] = fw[(c0 + u) * 9 + kk];
  }
  float a0 = 0.f, a1 = 0.f, a2 = 0.f, a3 = 0.f;
  const size_t rowbase = (size_t)bb * PP;
  #pragma unroll
  for (int kh = 0; kh < 3; ++kh) {
    int hh = h + kh - 1;
    if (hh < 0 || hh >= HH) continue;
    #pragma unroll
    for (int kw = 0; kw < 3; ++kw) {
      int wp = w + kw - 1;
      if (wp < 0 || wp >= WWD) continue;
      float4 v = *reinterpret_cast<const float4*>(IN + (rowbase + hh * WWD + wp) * CC + c0);
      int kk = kh * 3 + kw;
      a0 = fmaf(v.x, wreg[kk][0], a0);
      a1 = fmaf(v.y, wreg[kk][1], a1);
      a2 = fmaf(v.z, wreg[kk][2], a2);
      a3 = fmaf(v.w, wreg[kk][3], a3);
    }
  }
  float4 o;
  o.x = gelu_f(a0); o.y = gelu_f(a1); o.z = gelu_f(a2); o.w = gelu_f(a3);
  *reinterpret_cast<float4*>(OUT + (size_t)tk * CC + c0) = o;
}

// ---------------- depthwise 5x5 + gelu ----------------
__global__ __launch_bounds__(256) void k_dw5(const float* __restrict__ IN,
    const float* __restrict__ fw, float* __restrict__ OUT)
{
  int idx = blockIdx.x * 256 + threadIdx.x;
  int tk = idx / 48;
  int cq = idx - tk * 48;
  if (tk >= NTOK) return;
  int c0 = cq << 2;
  int bb = tk / PP;
  int hw = tk - bb * PP;
  int h = hw / WWD;
  int w = hw - h * WWD;
  float a0 = 0.f, a1 = 0.f, a2 = 0.f, a3 = 0.f;
  const size_t rowbase = (size_t)bb * PP;
  #pragma unroll
  for (int kh = 0; kh < 5; ++kh) {
    int hh = h + kh - 2;
    if (hh < 0 || hh >= HH) continue;
    #pragma unroll
    for (int kw = 0; kw < 5; ++kw) {
      int wp = w + kw - 2;
      if (wp < 0 || wp >= WWD) continue;
      float4 v = *reinterpret_cast<const float4*>(IN + (rowbase + hh * WWD + wp) * CC + c0);
      int kk = kh * 5 + kw;
      a0 = fmaf(v.x, fw[(c0 + 0) * 25 + kk], a0);
      a1 = fmaf(v.y, fw[(c0 + 1) * 25 + kk], a1);
      a2 = fmaf(v.z, fw[(c0 + 2) * 25 + kk], a2);
      a3 = fmaf(v.w, fw[(c0 + 3) * 25 + kk], a3);
    }
  }
  float4 o;
  o.x = gelu_f(a0); o.y = gelu_f(a1); o.z = gelu_f(a2); o.w = gelu_f(a3);
  *reinterpret_cast<float4*>(OUT + (size_t)tk * CC + c0) = o;
}

// ---------------- spatial global mean (two-pass) ----------------
__global__ __launch_bounds__(192) void k_mean(const float* __restrict__ C2S,
                                              float* __restrict__ GMpart)
{
  int bb = blockIdx.x / 49;
  int chunk = blockIdx.x - bb * 49;
  int c = threadIdx.x;
  float s = 0.f;
  int hw0 = chunk * 64;
  const float* p = C2S + ((size_t)bb * PP + hw0) * CC + c;
  for (int i = 0; i < 64; ++i) s += p[(size_t)i * CC];
  GMpart[(size_t)chunk * 6144 + bb * CC + c] = s;
}

__global__ __launch_bounds__(256) void k_gmg(const float* __restrict__ GMpart,
                                             float* __restrict__ GMg)
{
  int i = blockIdx.x * 256 + threadIdx.x;
  if (i >= 6144) return;
  float s = 0.f;
  for (int p = 0; p < 49; ++p) s += GMpart[(size_t)p * 6144 + i];
  GMg[i] = gelu_f(s * (1.0f / 3136.0f));
}

// ================= mod GEMM (pipelined split-bf16 MFMA), in-place over C1 =================
__global__ __launch_bounds__(256, 3) void k_mod_mfma(float* __restrict__ C1MOD,
    const float* __restrict__ C2S, const float* __restrict__ GS,
    const float* __restrict__ GMg,
    const u16* __restrict__ Wmh, const u16* __restrict__ Wml,
    const float* __restrict__ bh)
{
  __shared__ __align__(16) u16 sh_[32 * 200];
  __shared__ __align__(16) u16 sl_[32 * 200];
  const int tid  = threadIdx.x;
  const int lane = tid & 63;
  const int w    = tid >> 6;
  const int lrow = lane & 15;
  const int lk   = (lane >> 4) * 8;
  const int orow = (lane >> 4) * 4;
  const int tk0  = blockIdx.x * 32;
  const int m0   = w * 48;

  #pragma unroll
  for (int it = 0; it < 6; ++it) {
    int idx = tid + it * 256;
    int tokl = idx / 48;
    int c = (idx - tokl * 48) * 4;
    int tok = tk0 + tokl;
    int bb = tok / PP;
    size_t base = (size_t)tok * CC + c;
    float4 v1 = *(const float4*)(C1MOD + base);
    float4 v2 = *(const float4*)(C2S + base);
    float4 vg = *(const float4*)(GMg + bb * CC + c);
    float g0 = GS[(size_t)tok * 3 + 0];
    float g1 = GS[(size_t)tok * 3 + 1];
    float g2 = GS[(size_t)tok * 3 + 2];
    float4 av = make_float4(v1.x * g0 + v2.x * g1 + vg.x * g2,
                            v1.y * g0 + v2.y * g1 + vg.y * g2,
                            v1.z * g0 + v2.z * g1 + vg.z * g2,
                            v1.w * g0 + v2.w * g1 + vg.w * g2);
    split4(av, (uint2*)&sh_[tokl * 200 + c], (uint2*)&sl_[tokl * 200 + c]);
  }
  __syncthreads();

#define LOADA_G(WH, WL, KB, AH, AL) { \
    _Pragma("unroll") for (int r = 0; r < 3; ++r) { \
      size_t aoff = (size_t)(m0 + r * 16 + lrow) * 192 + (KB) * 32 + lk; \
      AH[r] = *(const short8v*)(WH + aoff); \
      AL[r] = *(const short8v*)(WL + aoff); } }
#define LOADB_G(KB, BH, BL) { \
    _Pragma("unroll") for (int c = 0; c < 2; ++c) { \
      int tokl = c * 16 + lrow; \
      BH[c] = *(const short8v*)&sh_[tokl * 200 + (KB) * 32 + lk]; \
      BL[c] = *(const short8v*)&sl_[tokl * 200 + (KB) * 32 + lk]; } }

  f32x4 acc[3][2] = {};
  short8v ahb[2][3], alb[2][3], bhb[2][2], blb[2][2];
  LOADA_G(Wmh, Wml, 0, ahb[0], alb[0]);
  LOADB_G(0, bhb[0], blb[0]);
  #pragma unroll
  for (int kb = 0; kb < 6; ++kb) {
    const int cur = kb & 1, nxt = cur ^ 1;
    if (kb + 1 < 6) {
      LOADA_G(Wmh, Wml, kb + 1, ahb[nxt], alb[nxt]);
      LOADB_G(kb + 1, bhb[nxt], blb[nxt]);
    }
    #pragma unroll
    for (int r = 0; r < 3; ++r)
      #pragma unroll
      for (int c = 0; c < 2; ++c) {
        acc[r][c] = __builtin_amdgcn_mfma_f32_16x16x32_bf16(ahb[cur][r], bhb[cur][c], acc[r][c], 0, 0, 0);
        acc[r][c] = __builtin_amdgcn_mfma_f32_16x16x32_bf16(ahb[cur][r], blb[cur][c], acc[r][c], 0, 0, 0);
        acc[r][c] = __builtin_amdgcn_mfma_f32_16x16x32_bf16(alb[cur][r], bhb[cur][c], acc[r][c], 0, 0, 0);
      }
  }
  __syncthreads();   // all reads of C1MOD rows complete before in-place writes

  #pragma unroll
  for (int r = 0; r < 3; ++r) {
    int jb = m0 + r * 16 + orow;
    float4 b4 = *(const float4*)&bh[jb];
    #pragma unroll
    for (int c = 0; c < 2; ++c) {
      int tok = tk0 + c * 16 + lrow;
      f32x4 a = acc[r][c];
      *(float4*)&C1MOD[(size_t)tok * CC + jb] =
          make_float4(a[0] + b4.x, a[1] + b4.y, a[2] + b4.z, a[3] + b4.w);
    }
  }
}

// ================= output GEMM (pipelined split-bf16 MFMA), in-place over MT =================
__global__ __launch_bounds__(256, 3) void k_out_mfma(const float* __restrict__ QS,
    const float* __restrict__ MOD, float* MTout,
    const u16* __restrict__ Wph, const u16* __restrict__ Wpl,
    const float* __restrict__ bp)
{
  __shared__ __align__(16) u16 sh_[32 * 200];
  __shared__ __align__(16) u16 sl_[32 * 200];
  const int tid  = threadIdx.x;
  const int lane = tid & 63;
  const int w    = tid >> 6;
  const int lrow = lane & 15;
  const int lk   = (lane >> 4) * 8;
  const int orow = (lane >> 4) * 4;
  const int tk0  = blockIdx.x * 32;
  const int m0   = w * 48;

  #pragma unroll
  for (int it = 0; it < 6; ++it) {
    int idx = tid + it * 256;
    int tokl = idx / 48;
    int c = (idx - tokl * 48) * 4;
    size_t base = (size_t)(tk0 + tokl) * CC + c;
    float4 q  = *(const float4*)(QS + base);
    float4 md = *(const float4*)(MOD + base);
    float4 mt = *(const float4*)(MTout + base);
    float4 av = make_float4(q.x * md.x * mt.x, q.y * md.y * mt.y,
                            q.z * md.z * mt.z, q.w * md.w * mt.w);
    split4(av, (uint2*)&sh_[tokl * 200 + c], (uint2*)&sl_[tokl * 200 + c]);
  }
  __syncthreads();

  f32x4 acc[3][2] = {};
  short8v ahb[2][3], alb[2][3], bhb[2][2], blb[2][2];
  LOADA_G(Wph, Wpl, 0, ahb[0], alb[0]);
  LOADB_G(0, bhb[0], blb[0]);
  #pragma unroll
  for (int kb = 0; kb < 6; ++kb) {
    const int cur = kb & 1, nxt = cur ^ 1;
    if (kb + 1 < 6) {
      LOADA_G(Wph, Wpl, kb + 1, ahb[nxt], alb[nxt]);
      LOADB_G(kb + 1, bhb[nxt], blb[nxt]);
    }
    #pragma unroll
    for (int r = 0; r < 3; ++r)
      #pragma unroll
      for (int c = 0; c < 2; ++c) {
        acc[r][c] = __builtin_amdgcn_mfma_f32_16x16x32_bf16(ahb[cur][r], bhb[cur][c], acc[r][c], 0, 0, 0);
        acc[r][c] = __builtin_amdgcn_mfma_f32_16x16x32_bf16(ahb[cur][r], blb[cur][c], acc[r][c], 0, 0, 0);
        acc[r][c] = __builtin_amdgcn_mfma_f32_16x16x32_bf16(alb[cur][r], bhb[cur][c], acc[r][c], 0, 0, 0);
      }
  }
#undef LOADA_G
#undef LOADB_G
  __syncthreads();   // all MT reads complete before in-place writes

  #pragma unroll
  for (int r = 0; r < 3; ++r) {
    int jb = m0 + r * 16 + orow;
    float4 b4 = *(const float4*)&bp[jb];
    #pragma unroll
    for (int c = 0; c < 2; ++c) {
      int tok = tk0 + c * 16 + lrow;
      f32x4 a = acc[r][c];
      *(float4*)&MTout[(size_t)tok * CC + jb] =
          make_float4(a[0] + b4.x, a[1] + b4.y, a[2] + b4.z, a[3] + b4.w);
    }
  }
}

extern "C" void kernel_launch(void* const* d_in, const int* in_sizes, int n_in,
                              void* d_out, int out_size, void* d_ws, size_t ws_size,
                              hipStream_t stream)
{
  (void)in_sizes; (void)n_in; (void)out_size; (void)ws_size;
  const float* x   = (const float*)d_in[0];
  const float* Wf  = (const float*)d_in[1];
  const float* bf  = (const float*)d_in[2];
  const float* Wft = (const float*)d_in[3];
  const float* bft = (const float*)d_in[4];
  const float* fw0 = (const float*)d_in[5];
  const float* fw1 = (const float*)d_in[6];
  const float* tw0 = (const float*)d_in[7];
  const float* tw1 = (const float*)d_in[8];
  const float* Wh  = (const float*)d_in[9];
  const float* bh  = (const float*)d_in[10];
  const float* Wht = (const float*)d_in[11];
  const float* bht = (const float*)d_in[12];
  const float* Wp  = (const float*)d_in[13];
  const float* bp  = (const float*)d_in[14];

  float* ws = (float*)d_ws;
  const size_t SZ = (size_t)NTOK * CC;          // 19,267,584 floats (77 MB)
  float* QS     = ws + 0 * SZ;                  // q (spatial)
  float* WS1    = ws + 1 * SZ;                  // ctx_s -> c2_s
  float* WS2    = ws + 2 * SZ;                  // ctx_t -> c1_s -> MOD
  float* MT     = (float*)d_out;                // mod_t (spatial order) -> out, in-place
  float* GS     = ws + 3 * SZ;                  // gates_s [tok][3]
  float* GT     = GS + (size_t)NTOK * 3;        // gates_t [n*8+t][3]
  float* GMpart = GT + (size_t)NTOK * 3;        // 49 x 6144
  float* GMg    = GMpart + 49 * 6144;           // gelu(mean) [32][192]
  u16* W3h = (u16*)(GMg + 6144);                // conv3 [k][o][i] hi
  u16* W3l = W3h + 3 * 36864;
  u16* W5h = W3l + 3 * 36864;
  u16* W5l = W5h + 5 * 36864;
  u16* WHh = W5l + 5 * 36864;
  u16* WHl = WHh + 36864;
  u16* WIh = WHl + 36864;                       // input proj [j<768][k]
  u16* WIl = WIh + 768 * 192;
  u16* Wmh = WIl + 768 * 192;                   // Wh [o][c]
  u16* Wml = Wmh + 36864;
  u16* Wph = Wml + 36864;                       // Wp^T [o][c]
  u16* Wpl = Wph + 36864;

  k_wsplit<<<432, 256, 0, stream>>>(tw0, W3h, W3l, 3);
  k_wsplit<<<720, 256, 0, stream>>>(tw1, W5h, W5l, 5);
  k_wsplit<<<144, 256, 0, stream>>>(Wht, WHh, WHl, 1);
  k_wsplit_in<<<576, 256, 0, stream>>>(Wf, Wft, WIh, WIl);
  k_wsplit_d<<<144, 256, 0, stream>>>(Wh, Wmh, Wml);
  k_wsplit_t<<<144, 256, 0, stream>>>(Wp, Wph, Wpl);

  k_in_mfma<<<dim3(3136, 2), 256, 0, stream>>>(x, WIh, WIl, bf, bft,
                                               QS, WS1, GS, WS2, GT);
  k_t_mfma<<<3136, 256, 0, stream>>>(WS2, GT, W3h, W3l, W5h, W5l, WHh, WHl, bht, MT);

  k_dw3<<<18816, 256, 0, stream>>>(WS1, fw0, WS2);      // ctx -> c1 (over ctx_t)
  k_dw5<<<18816, 256, 0, stream>>>(WS2, fw1, WS1);      // c1  -> c2 (over ctx)
  k_mean<<<32 * 49, 192, 0, stream>>>(WS1, GMpart);
  k_gmg<<<24, 256, 0, stream>>>(GMpart, GMg);

  k_mod_mfma<<<3136, 256, 0, stream>>>(WS2, WS1, GS, GMg, Wmh, Wml, bh);   // MOD over C1
  k_out_mfma<<<3136, 256, 0, stream>>>(QS, WS2, MT, Wph, Wpl, bp);         // out over MT
}